// Round 1
// baseline (1069.302 us; speedup 1.0000x reference)
//
#include <hip/hip_runtime.h>

#define N_NODES 100000
#define N_EDGES 1200000
#define N_GRAPHS 256

// ---------------- degree ----------------
__global__ __launch_bounds__(256) void deg_kernel(const int* __restrict__ ei, float* __restrict__ cnt) {
    int e = blockIdx.x * 256 + threadIdx.x;
    if (e < N_EDGES) atomicAdd(&cnt[ei[N_EDGES + e]], 1.0f);
}

// ---------------- edge scatter, 8-dim (layer 1 input) ----------------
__global__ __launch_bounds__(256) void scatter8(const int* __restrict__ ei, const float* __restrict__ x,
                                                float* __restrict__ agg) {
    int t = blockIdx.x * 256 + threadIdx.x;          // E*8 = 9.6M
    int e = t >> 3, d = t & 7;
    if (e < N_EDGES) {
        int s  = ei[e];
        int dd = ei[N_EDGES + e];
        atomicAdd(&agg[dd * 8 + d], x[s * 8 + d]);
    }
}

// ---------------- edge scatter, 64-dim ----------------
__global__ __launch_bounds__(256) void scatter64(const int* __restrict__ ei, const float* __restrict__ h,
                                                 float* __restrict__ agg) {
    int t = blockIdx.x * 256 + threadIdx.x;          // E*64 = 76.8M
    int e = t >> 6, d = t & 63;
    int s  = ei[e];
    int dd = ei[N_EDGES + e];
    atomicAdd(&agg[dd * 64 + d], h[s * 64 + d]);
}

// ---------------- layer 1: h1 = relu(mean8 @ W1l + b1 + x @ W1r) ----------------
__global__ __launch_bounds__(256) void layer1_kernel(const float* __restrict__ x, const float* __restrict__ aggx,
                                                     const float* __restrict__ cnt,
                                                     const float* __restrict__ Wl, const float* __restrict__ b,
                                                     const float* __restrict__ Wr, float* __restrict__ out) {
    __shared__ float sx[4][8], sa[4][8], sinv[4];
    int tid = threadIdx.x;
    int n0 = blockIdx.x * 4;
    if (tid < 32) { int sub = tid >> 3, k = tid & 7; sx[sub][k] = x[(n0 + sub) * 8 + k]; }
    else if (tid < 64) { int q = tid - 32; int sub = q >> 3, k = q & 7; sa[sub][k] = aggx[(n0 + sub) * 8 + k]; }
    else if (tid < 68) { int sub = tid - 64; sinv[sub] = 1.0f / fmaxf(cnt[n0 + sub], 1.0f); }
    __syncthreads();
    int sub = tid >> 6, d = tid & 63;
    float al = 0.f, ar = 0.f;
#pragma unroll
    for (int k = 0; k < 8; k++) {
        al += sa[sub][k] * Wl[k * 64 + d];
        ar += sx[sub][k] * Wr[k * 64 + d];
    }
    float v = al * sinv[sub] + b[d] + ar;
    out[(n0 + sub) * 64 + d] = fmaxf(v, 0.0f);
}

// ---------------- layers 2/3: in-place over agg buffer ----------------
template <bool RELU>
__global__ __launch_bounds__(256) void layerN_kernel(const float* __restrict__ h, float* __restrict__ agg,
                                                     const float* __restrict__ cnt,
                                                     const float* __restrict__ Wl, const float* __restrict__ b,
                                                     const float* __restrict__ Wr) {
    __shared__ float sh[4][64], sa[4][64], sinv[4];
    int tid = threadIdx.x;
    int n0 = blockIdx.x * 4;
    int sub = tid >> 6, d = tid & 63;
    sh[sub][d] = h[(n0 + sub) * 64 + d];
    sa[sub][d] = agg[(n0 + sub) * 64 + d];
    if (tid < 4) sinv[tid] = 1.0f / fmaxf(cnt[n0 + tid], 1.0f);
    __syncthreads();
    float al = 0.f, ar = 0.f;
#pragma unroll 8
    for (int k = 0; k < 64; k++) {
        al += sa[sub][k] * Wl[k * 64 + d];
        ar += sh[sub][k] * Wr[k * 64 + d];
    }
    float v = al * sinv[sub] + b[d] + ar;
    if (RELU) v = fmaxf(v, 0.0f);
    agg[(n0 + sub) * 64 + d] = v;
}

// ---------------- global add pool ----------------
__global__ __launch_bounds__(256) void pool_kernel(const float* __restrict__ h, const int* __restrict__ batch,
                                                   float* __restrict__ g) {
    int t = blockIdx.x * 256 + threadIdx.x;          // N*64 = 6.4M
    int n = t >> 6, d = t & 63;
    atomicAdd(&g[batch[n] * 64 + d], h[t]);
}

// ---------------- head: relu(g@Wc1+bc1)@Wc2+bc2 ----------------
__global__ __launch_bounds__(256) void head_kernel(const float* __restrict__ g, const float* __restrict__ Wc1,
                                                   const float* __restrict__ bc1, const float* __restrict__ Wc2,
                                                   const float* __restrict__ bc2, float* __restrict__ out) {
    int gid = threadIdx.x;                            // 256 graphs, one block
    const float* gr = g + gid * 64;
    float o = bc2[0];
#pragma unroll 4
    for (int j = 0; j < 32; j++) {
        float a = bc1[j];
#pragma unroll 8
        for (int k = 0; k < 64; k++) a += gr[k] * Wc1[k * 32 + j];
        o += fmaxf(a, 0.0f) * Wc2[j];
    }
    out[gid] = o;
}

extern "C" void kernel_launch(void* const* d_in, const int* in_sizes, int n_in,
                              void* d_out, int out_size, void* d_ws, size_t ws_size,
                              hipStream_t stream) {
    const float* x   = (const float*)d_in[0];
    const int*   ei  = (const int*)d_in[1];
    const int*   bat = (const int*)d_in[2];
    const float* W1l = (const float*)d_in[3];
    const float* b1  = (const float*)d_in[4];
    const float* W1r = (const float*)d_in[5];
    const float* W2l = (const float*)d_in[6];
    const float* b2  = (const float*)d_in[7];
    const float* W2r = (const float*)d_in[8];
    const float* W3l = (const float*)d_in[9];
    const float* b3  = (const float*)d_in[10];
    const float* W3r = (const float*)d_in[11];
    const float* Wc1 = (const float*)d_in[12];
    const float* bc1 = (const float*)d_in[13];
    const float* Wc2 = (const float*)d_in[14];
    const float* bc2 = (const float*)d_in[15];

    float* ws = (float*)d_ws;
    // ws layout (float offsets)
    float* cnt  = ws;                      // N
    float* g    = ws + 100352;             // 256*64 = 16384
    float* aggx = ws + 116736;             // N*8 = 800000 (padded to 802816)
    float* bufA = ws + 919552;             // N*64
    float* bufB = ws + 7319552;            // N*64

    // zero accumulators (ws is poisoned 0xAA every call)
    hipMemsetAsync(cnt,  0, (size_t)N_NODES * 4, stream);
    hipMemsetAsync(g,    0, (size_t)N_GRAPHS * 64 * 4, stream);
    hipMemsetAsync(aggx, 0, (size_t)N_NODES * 8 * 4, stream);

    deg_kernel<<<(N_EDGES + 255) / 256, 256, 0, stream>>>(ei, cnt);
    scatter8<<<N_EDGES * 8 / 256, 256, 0, stream>>>(ei, x, aggx);
    layer1_kernel<<<N_NODES / 4, 256, 0, stream>>>(x, aggx, cnt, W1l, b1, W1r, bufA);

    hipMemsetAsync(bufB, 0, (size_t)N_NODES * 64 * 4, stream);
    scatter64<<<N_EDGES * 64 / 256, 256, 0, stream>>>(ei, bufA, bufB);
    layerN_kernel<true><<<N_NODES / 4, 256, 0, stream>>>(bufA, bufB, cnt, W2l, b2, W2r);

    hipMemsetAsync(bufA, 0, (size_t)N_NODES * 64 * 4, stream);
    scatter64<<<N_EDGES * 64 / 256, 256, 0, stream>>>(ei, bufB, bufA);
    layerN_kernel<false><<<N_NODES / 4, 256, 0, stream>>>(bufB, bufA, cnt, W3l, b3, W3r);

    pool_kernel<<<N_NODES * 64 / 256, 256, 0, stream>>>(bufA, bat, g);
    head_kernel<<<1, 256, 0, stream>>>(g, Wc1, bc1, Wc2, bc2, (float*)d_out);
}

// Round 2
// 835.341 us; speedup vs baseline: 1.2801x; 1.2801x over previous
//
#include <hip/hip_runtime.h>

#define N_NODES 100000
#define N_EDGES 1200000
#define N_GRAPHS 256

// ---------------- degree histogram (int atomics) ----------------
__global__ __launch_bounds__(256) void hist_kernel(const int* __restrict__ ei, int* __restrict__ ideg) {
    int e = blockIdx.x * 256 + threadIdx.x;
    if (e < N_EDGES) atomicAdd(&ideg[ei[N_EDGES + e]], 1);
}

// ---------------- single-block exclusive scan -> rowptr + cursor ----------------
__global__ __launch_bounds__(256) void scan_kernel(const int* __restrict__ ideg, int* __restrict__ rowptr,
                                                   int* __restrict__ cursor) {
    __shared__ int ssum[256];
    int tid = threadIdx.x;
    const int CH = (N_NODES + 255) / 256;  // 391
    int begin = tid * CH;
    int end = begin + CH; if (end > N_NODES) end = N_NODES;
    int s = 0;
    for (int i = begin; i < end; i++) s += ideg[i];
    ssum[tid] = s;
    __syncthreads();
    for (int off = 1; off < 256; off <<= 1) {
        int v = (tid >= off) ? ssum[tid - off] : 0;
        __syncthreads();
        ssum[tid] += v;
        __syncthreads();
    }
    int run = (tid == 0) ? 0 : ssum[tid - 1];
    for (int i = begin; i < end; i++) {
        rowptr[i] = run;
        cursor[i] = run;
        run += ideg[i];
    }
    if (tid == 255) rowptr[N_NODES] = run;
}

// ---------------- fill CSR src list ----------------
__global__ __launch_bounds__(256) void fill_kernel(const int* __restrict__ ei, int* __restrict__ cursor,
                                                   int* __restrict__ esrc) {
    int e = blockIdx.x * 256 + threadIdx.x;
    if (e < N_EDGES) {
        int dd = ei[N_EDGES + e];
        int pos = atomicAdd(&cursor[dd], 1);
        esrc[pos] = ei[e];
    }
}

// ---------------- layer 1 fused: gather-mean(x,8) + relu(mean@W1l + b1 + x@W1r) ----------------
__global__ __launch_bounds__(256) void layer1_fused(const float* __restrict__ x, const int* __restrict__ rowptr,
                                                    const int* __restrict__ esrc,
                                                    const float* __restrict__ Wl, const float* __restrict__ b,
                                                    const float* __restrict__ Wr, float* __restrict__ out) {
    __shared__ float sa[4][8], sx[4][8];
    int tid = threadIdx.x;
    int sub = tid >> 6, lane = tid & 63;
    int j = lane >> 3, k = lane & 7;      // 8 parallel edges x 8 dims
    int n = blockIdx.x * 4 + sub;
    int r0 = rowptr[n], r1 = rowptr[n + 1];
    float acc = 0.f;
    for (int e = r0 + j; e < r1; e += 8) {
        int s = esrc[e];
        acc += x[s * 8 + k];
    }
    acc += __shfl_xor(acc, 8);
    acc += __shfl_xor(acc, 16);
    acc += __shfl_xor(acc, 32);           // reduce over j; every lane now has sum for its k
    float invn = 1.0f / fmaxf((float)(r1 - r0), 1.0f);
    if (lane < 8) { sa[sub][lane] = acc * invn; sx[sub][lane] = x[n * 8 + lane]; }
    __syncthreads();
    float al = 0.f, ar = 0.f;
#pragma unroll
    for (int kk = 0; kk < 8; kk++) {
        al += sa[sub][kk] * Wl[kk * 64 + lane];
        ar += sx[sub][kk] * Wr[kk * 64 + lane];
    }
    out[n * 64 + lane] = fmaxf(al + b[lane] + ar, 0.0f);
}

// ---------------- layers 2/3 fused: gather-mean(h,64) + linear(s) ----------------
template <bool RELU>
__global__ __launch_bounds__(256) void layerN_fused(const float* __restrict__ h, const int* __restrict__ rowptr,
                                                    const int* __restrict__ esrc,
                                                    const float* __restrict__ Wl, const float* __restrict__ b,
                                                    const float* __restrict__ Wr, float* __restrict__ out) {
    __shared__ float sh[4][64], sa[4][64];
    int tid = threadIdx.x;
    int sub = tid >> 6, d = tid & 63;
    int n = blockIdx.x * 4 + sub;         // wave per node: no intra-wave divergence
    int r0 = rowptr[n], r1 = rowptr[n + 1];
    float a0 = 0.f, a1 = 0.f, a2 = 0.f, a3 = 0.f;
    int e = r0;
    for (; e + 4 <= r1; e += 4) {         // 4-way MLP on the gather
        int s0 = esrc[e], s1 = esrc[e + 1], s2 = esrc[e + 2], s3 = esrc[e + 3];
        a0 += h[s0 * 64 + d];
        a1 += h[s1 * 64 + d];
        a2 += h[s2 * 64 + d];
        a3 += h[s3 * 64 + d];
    }
    for (; e < r1; e++) a0 += h[esrc[e] * 64 + d];
    float invn = 1.0f / fmaxf((float)(r1 - r0), 1.0f);
    sa[sub][d] = (a0 + a1 + a2 + a3) * invn;
    sh[sub][d] = h[n * 64 + d];
    __syncthreads();
    float al = 0.f, ar = 0.f;
#pragma unroll 8
    for (int k = 0; k < 64; k++) {
        al += sa[sub][k] * Wl[k * 64 + d];
        ar += sh[sub][k] * Wr[k * 64 + d];
    }
    float v = al + b[d] + ar;
    if (RELU) v = fmaxf(v, 0.0f);
    out[n * 64 + d] = v;
}

// ---------------- global add pool: accumulate along sorted batch, flush on change ----------------
__global__ __launch_bounds__(256) void pool_kernel(const float* __restrict__ h, const int* __restrict__ batch,
                                                   float* __restrict__ g) {
    int d = threadIdx.x & 63;
    int grp = threadIdx.x >> 6;           // 4 node-lanes
    int n0 = blockIdx.x * 256;
    int cur = -1; float acc = 0.f;
    for (int i = grp; i < 256; i += 4) {
        int n = n0 + i;
        if (n >= N_NODES) break;
        int bb = batch[n];
        if (bb != cur) {
            if (cur >= 0) atomicAdd(&g[cur * 64 + d], acc);
            cur = bb; acc = 0.f;
        }
        acc += h[n * 64 + d];
    }
    if (cur >= 0) atomicAdd(&g[cur * 64 + d], acc);
}

// ---------------- head ----------------
__global__ __launch_bounds__(256) void head_kernel(const float* __restrict__ g, const float* __restrict__ Wc1,
                                                   const float* __restrict__ bc1, const float* __restrict__ Wc2,
                                                   const float* __restrict__ bc2, float* __restrict__ out) {
    int gid = threadIdx.x;
    const float* gr = g + gid * 64;
    float o = bc2[0];
#pragma unroll 4
    for (int j = 0; j < 32; j++) {
        float a = bc1[j];
#pragma unroll 8
        for (int k = 0; k < 64; k++) a += gr[k] * Wc1[k * 32 + j];
        o += fmaxf(a, 0.0f) * Wc2[j];
    }
    out[gid] = o;
}

extern "C" void kernel_launch(void* const* d_in, const int* in_sizes, int n_in,
                              void* d_out, int out_size, void* d_ws, size_t ws_size,
                              hipStream_t stream) {
    const float* x   = (const float*)d_in[0];
    const int*   ei  = (const int*)d_in[1];
    const int*   bat = (const int*)d_in[2];
    const float* W1l = (const float*)d_in[3];
    const float* b1  = (const float*)d_in[4];
    const float* W1r = (const float*)d_in[5];
    const float* W2l = (const float*)d_in[6];
    const float* b2  = (const float*)d_in[7];
    const float* W2r = (const float*)d_in[8];
    const float* W3l = (const float*)d_in[9];
    const float* b3  = (const float*)d_in[10];
    const float* W3r = (const float*)d_in[11];
    const float* Wc1 = (const float*)d_in[12];
    const float* bc1 = (const float*)d_in[13];
    const float* Wc2 = (const float*)d_in[14];
    const float* bc2 = (const float*)d_in[15];

    float* ws = (float*)d_ws;
    // layout (float offsets); ideg aliases bufA, cursor aliases bufB (dead before first write)
    int*   rowptr = (int*)(ws);                 // 100001 (pad 100352)
    int*   esrc   = (int*)(ws + 100352);        // 1200000 (pad 1200128)
    float* g      = ws + 1300480;               // 16384
    float* bufA   = ws + 1316864;               // 6400000
    float* bufB   = ws + 7716864;               // 6400000
    int*   ideg   = (int*)bufA;                 // alias: dead after scan, before layer1 writes bufA
    int*   cursor = (int*)bufB;                 // alias: dead after fill, before layer2 writes bufB

    hipMemsetAsync(ideg, 0, (size_t)N_NODES * 4, stream);
    hipMemsetAsync(g,    0, (size_t)N_GRAPHS * 64 * 4, stream);

    hist_kernel<<<(N_EDGES + 255) / 256, 256, 0, stream>>>(ei, ideg);
    scan_kernel<<<1, 256, 0, stream>>>(ideg, rowptr, cursor);
    fill_kernel<<<(N_EDGES + 255) / 256, 256, 0, stream>>>(ei, cursor, esrc);

    layer1_fused<<<N_NODES / 4, 256, 0, stream>>>(x, rowptr, esrc, W1l, b1, W1r, bufA);
    layerN_fused<true ><<<N_NODES / 4, 256, 0, stream>>>(bufA, rowptr, esrc, W2l, b2, W2r, bufB);
    layerN_fused<false><<<N_NODES / 4, 256, 0, stream>>>(bufB, rowptr, esrc, W3l, b3, W3r, bufA);

    pool_kernel<<<(N_NODES + 255) / 256, 256, 0, stream>>>(bufA, bat, g);
    head_kernel<<<1, 256, 0, stream>>>(g, Wc1, bc1, Wc2, bc2, (float*)d_out);
}

// Round 3
// 565.609 us; speedup vs baseline: 1.8905x; 1.4769x over previous
//
#include <hip/hip_runtime.h>

#define N_NODES 100000
#define N_EDGES 1200000
#define N_GRAPHS 256
#define NBLK 98              // ceil(100000/1024)

// ---------------- degree histogram (int atomics) ----------------
__global__ __launch_bounds__(256) void hist_kernel(const int* __restrict__ ei, int* __restrict__ ideg) {
    int e = blockIdx.x * 256 + threadIdx.x;
    if (e < N_EDGES) atomicAdd(&ideg[ei[N_EDGES + e]], 1);
}

// ---------------- parallel scan, phase 1: per-block sums (1024 elems/block) ----------------
__global__ __launch_bounds__(256) void scan_part(const int* __restrict__ ideg, int* __restrict__ bsum) {
    __shared__ int red[256];
    int b = blockIdx.x, tid = threadIdx.x;
    int base = b * 1024 + tid * 4;
    int s = 0;
#pragma unroll
    for (int i = 0; i < 4; i++) s += (base + i < N_NODES) ? ideg[base + i] : 0;
    red[tid] = s;
    __syncthreads();
    for (int off = 128; off > 0; off >>= 1) {
        if (tid < off) red[tid] += red[tid + off];
        __syncthreads();
    }
    if (tid == 0) bsum[b] = red[0];
}

// ---------------- phase 2: exclusive scan of the 98 block sums ----------------
__global__ __launch_bounds__(128) void scan_block(int* __restrict__ bsum) {
    __shared__ int tmp[128];
    int tid = threadIdx.x;
    int v = (tid < NBLK) ? bsum[tid] : 0;
    tmp[tid] = v;
    __syncthreads();
    int acc = v;
    for (int off = 1; off < 128; off <<= 1) {
        int t = (tid >= off) ? tmp[tid - off] : 0;
        __syncthreads();
        tmp[tid] = acc = acc + t;
        __syncthreads();
    }
    if (tid < NBLK) bsum[tid] = acc - v;   // exclusive
}

// ---------------- phase 3: local scan + global offset -> rowptr, cursor ----------------
__global__ __launch_bounds__(256) void scan_final(const int* __restrict__ ideg, const int* __restrict__ bsum,
                                                  int* __restrict__ rowptr, int* __restrict__ cursor) {
    __shared__ int tsum[256];
    int b = blockIdx.x, tid = threadIdx.x;
    int base = b * 1024 + tid * 4;
    int v[4];
#pragma unroll
    for (int i = 0; i < 4; i++) v[i] = (base + i < N_NODES) ? ideg[base + i] : 0;
    int s = v[0] + v[1] + v[2] + v[3];
    tsum[tid] = s;
    __syncthreads();
    int acc = s;
    for (int off = 1; off < 256; off <<= 1) {
        int t = (tid >= off) ? tsum[tid - off] : 0;
        __syncthreads();
        tsum[tid] = acc = acc + t;
        __syncthreads();
    }
    int off = bsum[b] + acc - s;           // exclusive offset for this thread's 4 elems
#pragma unroll
    for (int i = 0; i < 4; i++) {
        if (base + i < N_NODES) { rowptr[base + i] = off; cursor[base + i] = off; off += v[i]; }
    }
    if (b == 0 && tid == 0) rowptr[N_NODES] = N_EDGES;  // sum of degrees is exactly E
}

// ---------------- fill CSR src list ----------------
__global__ __launch_bounds__(256) void fill_kernel(const int* __restrict__ ei, int* __restrict__ cursor,
                                                   int* __restrict__ esrc) {
    int e = blockIdx.x * 256 + threadIdx.x;
    if (e < N_EDGES) {
        int dd = ei[N_EDGES + e];
        int pos = atomicAdd(&cursor[dd], 1);
        esrc[pos] = ei[e];
    }
}

// ---------------- layer 1 fused: gather-mean(x,8) + relu(mean@W1l + b1 + x@W1r) ----------------
__global__ __launch_bounds__(256) void layer1_fused(const float* __restrict__ x, const int* __restrict__ rowptr,
                                                    const int* __restrict__ esrc,
                                                    const float* __restrict__ Wl, const float* __restrict__ b,
                                                    const float* __restrict__ Wr, float* __restrict__ out) {
    __shared__ float sa[4][8], sx[4][8];
    int tid = threadIdx.x;
    int sub = tid >> 6, lane = tid & 63;
    int j = lane >> 3, k = lane & 7;      // 8 parallel edges x 8 dims
    int n = blockIdx.x * 4 + sub;
    int r0 = rowptr[n], r1 = rowptr[n + 1];
    float acc = 0.f;
    for (int e = r0 + j; e < r1; e += 8) {
        int s = esrc[e];
        acc += x[s * 8 + k];
    }
    acc += __shfl_xor(acc, 8);
    acc += __shfl_xor(acc, 16);
    acc += __shfl_xor(acc, 32);           // reduce over j
    float invn = 1.0f / fmaxf((float)(r1 - r0), 1.0f);
    if (lane < 8) { sa[sub][lane] = acc * invn; sx[sub][lane] = x[n * 8 + lane]; }
    __syncthreads();
    float al = 0.f, ar = 0.f;
#pragma unroll
    for (int kk = 0; kk < 8; kk++) {
        al += sa[sub][kk] * Wl[kk * 64 + lane];
        ar += sx[sub][kk] * Wr[kk * 64 + lane];
    }
    out[n * 64 + lane] = fmaxf(al + b[lane] + ar, 0.0f);
}

// ---------------- layers 2/3 fused: gather-mean(h,64) + linear(s) ----------------
template <bool RELU>
__global__ __launch_bounds__(256) void layerN_fused(const float* __restrict__ h, const int* __restrict__ rowptr,
                                                    const int* __restrict__ esrc,
                                                    const float* __restrict__ Wl, const float* __restrict__ b,
                                                    const float* __restrict__ Wr, float* __restrict__ out) {
    __shared__ float sh[4][64], sa[4][64];
    int tid = threadIdx.x;
    int sub = tid >> 6, d = tid & 63;
    int n = blockIdx.x * 4 + sub;         // wave per node
    int r0 = rowptr[n], r1 = rowptr[n + 1];
    float a0 = 0.f, a1 = 0.f, a2 = 0.f, a3 = 0.f;
    int e = r0;
    for (; e + 4 <= r1; e += 4) {
        int s0 = esrc[e], s1 = esrc[e + 1], s2 = esrc[e + 2], s3 = esrc[e + 3];
        a0 += h[s0 * 64 + d];
        a1 += h[s1 * 64 + d];
        a2 += h[s2 * 64 + d];
        a3 += h[s3 * 64 + d];
    }
    for (; e < r1; e++) a0 += h[esrc[e] * 64 + d];
    float invn = 1.0f / fmaxf((float)(r1 - r0), 1.0f);
    sa[sub][d] = (a0 + a1 + a2 + a3) * invn;
    sh[sub][d] = h[n * 64 + d];
    __syncthreads();
    float al = 0.f, ar = 0.f;
#pragma unroll 8
    for (int k = 0; k < 64; k++) {
        al += sa[sub][k] * Wl[k * 64 + d];
        ar += sh[sub][k] * Wr[k * 64 + d];
    }
    float v = al + b[d] + ar;
    if (RELU) v = fmaxf(v, 0.0f);
    out[n * 64 + d] = v;
}

// ---------------- global add pool: accumulate along sorted batch, flush on change ----------------
__global__ __launch_bounds__(256) void pool_kernel(const float* __restrict__ h, const int* __restrict__ batch,
                                                   float* __restrict__ g) {
    int d = threadIdx.x & 63;
    int grp = threadIdx.x >> 6;
    int n0 = blockIdx.x * 256;
    int cur = -1; float acc = 0.f;
    for (int i = grp; i < 256; i += 4) {
        int n = n0 + i;
        if (n >= N_NODES) break;
        int bb = batch[n];
        if (bb != cur) {
            if (cur >= 0) atomicAdd(&g[cur * 64 + d], acc);
            cur = bb; acc = 0.f;
        }
        acc += h[n * 64 + d];
    }
    if (cur >= 0) atomicAdd(&g[cur * 64 + d], acc);
}

// ---------------- head: one wave per graph, 64 blocks x 4 waves ----------------
__global__ __launch_bounds__(256) void head_kernel(const float* __restrict__ g, const float* __restrict__ Wc1,
                                                   const float* __restrict__ bc1, const float* __restrict__ Wc2,
                                                   const float* __restrict__ bc2, float* __restrict__ out) {
    __shared__ float sg[4][64];
    int tid = threadIdx.x, sub = tid >> 6, lane = tid & 63;
    int gid = blockIdx.x * 4 + sub;
    sg[sub][lane] = g[gid * 64 + lane];
    __syncthreads();
    int j = lane & 31, kh = lane >> 5;     // lane = (k-half, j)
    float a = 0.f;
#pragma unroll
    for (int kk = 0; kk < 32; kk++) {
        int k = kh * 32 + kk;
        a += sg[sub][k] * Wc1[k * 32 + j];
    }
    a += __shfl_xor(a, 32);                // combine k-halves; lanes<32 hold a_j
    float contrib = (lane < 32) ? fmaxf(a + bc1[j], 0.0f) * Wc2[j] : 0.0f;
    contrib += __shfl_xor(contrib, 16);
    contrib += __shfl_xor(contrib, 8);
    contrib += __shfl_xor(contrib, 4);
    contrib += __shfl_xor(contrib, 2);
    contrib += __shfl_xor(contrib, 1);
    if (lane == 0) out[gid] = contrib + bc2[0];
}

extern "C" void kernel_launch(void* const* d_in, const int* in_sizes, int n_in,
                              void* d_out, int out_size, void* d_ws, size_t ws_size,
                              hipStream_t stream) {
    const float* x   = (const float*)d_in[0];
    const int*   ei  = (const int*)d_in[1];
    const int*   bat = (const int*)d_in[2];
    const float* W1l = (const float*)d_in[3];
    const float* b1  = (const float*)d_in[4];
    const float* W1r = (const float*)d_in[5];
    const float* W2l = (const float*)d_in[6];
    const float* b2  = (const float*)d_in[7];
    const float* W2r = (const float*)d_in[8];
    const float* W3l = (const float*)d_in[9];
    const float* b3  = (const float*)d_in[10];
    const float* W3r = (const float*)d_in[11];
    const float* Wc1 = (const float*)d_in[12];
    const float* bc1 = (const float*)d_in[13];
    const float* Wc2 = (const float*)d_in[14];
    const float* bc2 = (const float*)d_in[15];

    float* ws = (float*)d_ws;
    // layout (float offsets)
    int*   rowptr = (int*)(ws);                 // 100001 used, pad to 100352
    int*   bsum   = (int*)(ws) + 100096;        // 98 ints in rowptr's pad (100096 > 100001)
    int*   esrc   = (int*)(ws + 100352);        // 1200000 (pad 1200128)
    float* g      = ws + 1300480;               // 16384
    float* bufA   = ws + 1316864;               // 6400000
    float* bufB   = ws + 7716864;               // 6400000
    int*   ideg   = (int*)bufA;                 // alias: dead before layer1 writes bufA
    int*   cursor = (int*)bufB;                 // alias: dead before layer2 writes bufB

    hipMemsetAsync(ideg, 0, (size_t)N_NODES * 4, stream);
    hipMemsetAsync(g,    0, (size_t)N_GRAPHS * 64 * 4, stream);

    hist_kernel<<<(N_EDGES + 255) / 256, 256, 0, stream>>>(ei, ideg);
    scan_part<<<NBLK, 256, 0, stream>>>(ideg, bsum);
    scan_block<<<1, 128, 0, stream>>>(bsum);
    scan_final<<<NBLK, 256, 0, stream>>>(ideg, bsum, rowptr, cursor);
    fill_kernel<<<(N_EDGES + 255) / 256, 256, 0, stream>>>(ei, cursor, esrc);

    layer1_fused<<<N_NODES / 4, 256, 0, stream>>>(x, rowptr, esrc, W1l, b1, W1r, bufA);
    layerN_fused<true ><<<N_NODES / 4, 256, 0, stream>>>(bufA, rowptr, esrc, W2l, b2, W2r, bufB);
    layerN_fused<false><<<N_NODES / 4, 256, 0, stream>>>(bufB, rowptr, esrc, W3l, b3, W3r, bufA);

    pool_kernel<<<(N_NODES + 255) / 256, 256, 0, stream>>>(bufA, bat, g);
    head_kernel<<<N_GRAPHS / 4, 256, 0, stream>>>(g, Wc1, bc1, Wc2, bc2, (float*)d_out);
}

// Round 4
// 534.027 us; speedup vs baseline: 2.0023x; 1.0591x over previous
//
#include <hip/hip_runtime.h>

#define N_NODES 100000
#define N_EDGES 1200000
#define N_GRAPHS 256
#define NBLK 98              // ceil(100000/1024)

// ---------------- degree histogram (int atomics) ----------------
__global__ __launch_bounds__(256) void hist_kernel(const int* __restrict__ ei, int* __restrict__ ideg) {
    int e = blockIdx.x * 256 + threadIdx.x;
    if (e < N_EDGES) atomicAdd(&ideg[ei[N_EDGES + e]], 1);
}

// ---------------- parallel scan, phase 1: per-block sums (1024 elems/block) ----------------
__global__ __launch_bounds__(256) void scan_part(const int* __restrict__ ideg, int* __restrict__ bsum) {
    __shared__ int red[256];
    int b = blockIdx.x, tid = threadIdx.x;
    int base = b * 1024 + tid * 4;
    int s = 0;
#pragma unroll
    for (int i = 0; i < 4; i++) s += (base + i < N_NODES) ? ideg[base + i] : 0;
    red[tid] = s;
    __syncthreads();
    for (int off = 128; off > 0; off >>= 1) {
        if (tid < off) red[tid] += red[tid + off];
        __syncthreads();
    }
    if (tid == 0) bsum[b] = red[0];
}

// ---------------- phase 2: exclusive scan of the 98 block sums ----------------
__global__ __launch_bounds__(128) void scan_block(int* __restrict__ bsum) {
    __shared__ int tmp[128];
    int tid = threadIdx.x;
    int v = (tid < NBLK) ? bsum[tid] : 0;
    tmp[tid] = v;
    __syncthreads();
    int acc = v;
    for (int off = 1; off < 128; off <<= 1) {
        int t = (tid >= off) ? tmp[tid - off] : 0;
        __syncthreads();
        tmp[tid] = acc = acc + t;
        __syncthreads();
    }
    if (tid < NBLK) bsum[tid] = acc - v;   // exclusive
}

// ---------------- phase 3: local scan + global offset -> rowptr, cursor ----------------
__global__ __launch_bounds__(256) void scan_final(const int* __restrict__ ideg, const int* __restrict__ bsum,
                                                  int* __restrict__ rowptr, int* __restrict__ cursor) {
    __shared__ int tsum[256];
    int b = blockIdx.x, tid = threadIdx.x;
    int base = b * 1024 + tid * 4;
    int v[4];
#pragma unroll
    for (int i = 0; i < 4; i++) v[i] = (base + i < N_NODES) ? ideg[base + i] : 0;
    int s = v[0] + v[1] + v[2] + v[3];
    tsum[tid] = s;
    __syncthreads();
    int acc = s;
    for (int off = 1; off < 256; off <<= 1) {
        int t = (tid >= off) ? tsum[tid - off] : 0;
        __syncthreads();
        tsum[tid] = acc = acc + t;
        __syncthreads();
    }
    int off = bsum[b] + acc - s;
#pragma unroll
    for (int i = 0; i < 4; i++) {
        if (base + i < N_NODES) { rowptr[base + i] = off; cursor[base + i] = off; off += v[i]; }
    }
    if (b == 0 && tid == 0) rowptr[N_NODES] = N_EDGES;
}

// ---------------- fill CSR src list ----------------
__global__ __launch_bounds__(256) void fill_kernel(const int* __restrict__ ei, int* __restrict__ cursor,
                                                   int* __restrict__ esrc) {
    int e = blockIdx.x * 256 + threadIdx.x;
    if (e < N_EDGES) {
        int dd = ei[N_EDGES + e];
        int pos = atomicAdd(&cursor[dd], 1);
        esrc[pos] = ei[e];
    }
}

// ---------------- layer 1 fused: gather-mean(x,8) + relu(mean@W1l + b1 + x@W1r) ----------------
__global__ __launch_bounds__(256) void layer1_fused(const float* __restrict__ x, const int* __restrict__ rowptr,
                                                    const int* __restrict__ esrc,
                                                    const float* __restrict__ Wl, const float* __restrict__ b,
                                                    const float* __restrict__ Wr, float* __restrict__ out) {
    __shared__ float sa[4][8], sx[4][8];
    int tid = threadIdx.x;
    int sub = tid >> 6, lane = tid & 63;
    int j = lane >> 3, k = lane & 7;      // 8 parallel edges x 8 dims
    int n = blockIdx.x * 4 + sub;
    int r0 = __builtin_amdgcn_readfirstlane(rowptr[n]);
    int r1 = __builtin_amdgcn_readfirstlane(rowptr[n + 1]);
    float acc = 0.f;
    for (int e = r0 + j; e < r1; e += 8) {
        int s = esrc[e];
        acc += x[s * 8 + k];
    }
    acc += __shfl_xor(acc, 8);
    acc += __shfl_xor(acc, 16);
    acc += __shfl_xor(acc, 32);           // reduce over j
    float invn = 1.0f / fmaxf((float)(r1 - r0), 1.0f);
    if (lane < 8) { sa[sub][lane] = acc * invn; sx[sub][lane] = x[n * 8 + lane]; }
    __syncthreads();
    float al = 0.f, ar = 0.f;
#pragma unroll
    for (int kk = 0; kk < 8; kk++) {
        al += sa[sub][kk] * Wl[kk * 64 + lane];
        ar += sx[sub][kk] * Wr[kk * 64 + lane];
    }
    out[n * 64 + lane] = fmaxf(al + b[lane] + ar, 0.0f);
}

// ---------------- layers 2/3 fused: gather-mean(h,64) with 8 loads in flight + linears ----------------
template <bool RELU>
__global__ __launch_bounds__(256) void layerN_fused(const float* __restrict__ h, const int* __restrict__ rowptr,
                                                    const int* __restrict__ esrc,
                                                    const float* __restrict__ Wl, const float* __restrict__ b,
                                                    const float* __restrict__ Wr, float* __restrict__ out) {
    __shared__ float sh[4][64], sa[4][64];
    int tid = threadIdx.x;
    int sub = tid >> 6, d = tid & 63;
    int n = blockIdx.x * 4 + sub;         // wave per node
    int r0 = __builtin_amdgcn_readfirstlane(rowptr[n]);
    int r1 = __builtin_amdgcn_readfirstlane(rowptr[n + 1]);
    float self = h[n * 64 + d];           // independent: issue early
    float acc = 0.f;
    int e = r0;
    for (; e + 8 <= r1; e += 8) {
        // wave-uniform indices -> scalar loads; 8 vector gathers issued back-to-back
        int s0 = esrc[e + 0], s1 = esrc[e + 1], s2 = esrc[e + 2], s3 = esrc[e + 3];
        int s4 = esrc[e + 4], s5 = esrc[e + 5], s6 = esrc[e + 6], s7 = esrc[e + 7];
        float v0 = h[s0 * 64 + d], v1 = h[s1 * 64 + d], v2 = h[s2 * 64 + d], v3 = h[s3 * 64 + d];
        float v4 = h[s4 * 64 + d], v5 = h[s5 * 64 + d], v6 = h[s6 * 64 + d], v7 = h[s7 * 64 + d];
        acc += ((v0 + v1) + (v2 + v3)) + ((v4 + v5) + (v6 + v7));
    }
    if (e + 4 <= r1) {
        int s0 = esrc[e + 0], s1 = esrc[e + 1], s2 = esrc[e + 2], s3 = esrc[e + 3];
        float v0 = h[s0 * 64 + d], v1 = h[s1 * 64 + d], v2 = h[s2 * 64 + d], v3 = h[s3 * 64 + d];
        acc += (v0 + v1) + (v2 + v3);
        e += 4;
    }
    for (; e < r1; e++) acc += h[esrc[e] * 64 + d];
    float invn = 1.0f / fmaxf((float)(r1 - r0), 1.0f);
    sa[sub][d] = acc * invn;
    sh[sub][d] = self;
    __syncthreads();
    float al = 0.f, ar = 0.f;
#pragma unroll 8
    for (int k = 0; k < 64; k++) {
        al += sa[sub][k] * Wl[k * 64 + d];
        ar += sh[sub][k] * Wr[k * 64 + d];
    }
    float v = al + b[d] + ar;
    if (RELU) v = fmaxf(v, 0.0f);
    out[n * 64 + d] = v;
}

// ---------------- global add pool: accumulate along sorted batch, flush on change ----------------
__global__ __launch_bounds__(256) void pool_kernel(const float* __restrict__ h, const int* __restrict__ batch,
                                                   float* __restrict__ g) {
    int d = threadIdx.x & 63;
    int grp = threadIdx.x >> 6;
    int n0 = blockIdx.x * 256;
    int cur = -1; float acc = 0.f;
    for (int i = grp; i < 256; i += 4) {
        int n = n0 + i;
        if (n >= N_NODES) break;
        int bb = batch[n];
        if (bb != cur) {
            if (cur >= 0) atomicAdd(&g[cur * 64 + d], acc);
            cur = bb; acc = 0.f;
        }
        acc += h[n * 64 + d];
    }
    if (cur >= 0) atomicAdd(&g[cur * 64 + d], acc);
}

// ---------------- head: one wave per graph, 64 blocks x 4 waves ----------------
__global__ __launch_bounds__(256) void head_kernel(const float* __restrict__ g, const float* __restrict__ Wc1,
                                                   const float* __restrict__ bc1, const float* __restrict__ Wc2,
                                                   const float* __restrict__ bc2, float* __restrict__ out) {
    __shared__ float sg[4][64];
    int tid = threadIdx.x, sub = tid >> 6, lane = tid & 63;
    int gid = blockIdx.x * 4 + sub;
    sg[sub][lane] = g[gid * 64 + lane];
    __syncthreads();
    int j = lane & 31, kh = lane >> 5;
    float a = 0.f;
#pragma unroll
    for (int kk = 0; kk < 32; kk++) {
        int k = kh * 32 + kk;
        a += sg[sub][k] * Wc1[k * 32 + j];
    }
    a += __shfl_xor(a, 32);
    float contrib = (lane < 32) ? fmaxf(a + bc1[j], 0.0f) * Wc2[j] : 0.0f;
    contrib += __shfl_xor(contrib, 16);
    contrib += __shfl_xor(contrib, 8);
    contrib += __shfl_xor(contrib, 4);
    contrib += __shfl_xor(contrib, 2);
    contrib += __shfl_xor(contrib, 1);
    if (lane == 0) out[gid] = contrib + bc2[0];
}

extern "C" void kernel_launch(void* const* d_in, const int* in_sizes, int n_in,
                              void* d_out, int out_size, void* d_ws, size_t ws_size,
                              hipStream_t stream) {
    const float* x   = (const float*)d_in[0];
    const int*   ei  = (const int*)d_in[1];
    const int*   bat = (const int*)d_in[2];
    const float* W1l = (const float*)d_in[3];
    const float* b1  = (const float*)d_in[4];
    const float* W1r = (const float*)d_in[5];
    const float* W2l = (const float*)d_in[6];
    const float* b2  = (const float*)d_in[7];
    const float* W2r = (const float*)d_in[8];
    const float* W3l = (const float*)d_in[9];
    const float* b3  = (const float*)d_in[10];
    const float* W3r = (const float*)d_in[11];
    const float* Wc1 = (const float*)d_in[12];
    const float* bc1 = (const float*)d_in[13];
    const float* Wc2 = (const float*)d_in[14];
    const float* bc2 = (const float*)d_in[15];

    float* ws = (float*)d_ws;
    int*   rowptr = (int*)(ws);                 // 100001 used, pad to 100352
    int*   bsum   = (int*)(ws) + 100096;        // 98 ints in rowptr's pad
    int*   esrc   = (int*)(ws + 100352);        // 1200000 (pad 1200128)
    float* g      = ws + 1300480;               // 16384
    float* bufA   = ws + 1316864;               // 6400000
    float* bufB   = ws + 7716864;               // 6400000
    int*   ideg   = (int*)bufA;                 // alias: dead before layer1 writes bufA
    int*   cursor = (int*)bufB;                 // alias: dead before layer2 writes bufB

    hipMemsetAsync(ideg, 0, (size_t)N_NODES * 4, stream);
    hipMemsetAsync(g,    0, (size_t)N_GRAPHS * 64 * 4, stream);

    hist_kernel<<<(N_EDGES + 255) / 256, 256, 0, stream>>>(ei, ideg);
    scan_part<<<NBLK, 256, 0, stream>>>(ideg, bsum);
    scan_block<<<1, 128, 0, stream>>>(bsum);
    scan_final<<<NBLK, 256, 0, stream>>>(ideg, bsum, rowptr, cursor);
    fill_kernel<<<(N_EDGES + 255) / 256, 256, 0, stream>>>(ei, cursor, esrc);

    layer1_fused<<<N_NODES / 4, 256, 0, stream>>>(x, rowptr, esrc, W1l, b1, W1r, bufA);
    layerN_fused<true ><<<N_NODES / 4, 256, 0, stream>>>(bufA, rowptr, esrc, W2l, b2, W2r, bufB);
    layerN_fused<false><<<N_NODES / 4, 256, 0, stream>>>(bufB, rowptr, esrc, W3l, b3, W3r, bufA);

    pool_kernel<<<(N_NODES + 255) / 256, 256, 0, stream>>>(bufA, bat, g);
    head_kernel<<<N_GRAPHS / 4, 256, 0, stream>>>(g, Wc1, bc1, Wc2, bc2, (float*)d_out);
}

// Round 5
// 509.520 us; speedup vs baseline: 2.0986x; 1.0481x over previous
//
#include <hip/hip_runtime.h>

#define N_NODES 100000
#define N_EDGES 1200000
#define N_GRAPHS 256
#define NBLK 98              // ceil(100000/1024)

// ---------------- degree histogram (int atomics) ----------------
__global__ __launch_bounds__(256) void hist_kernel(const int* __restrict__ ei, int* __restrict__ ideg) {
    int e = blockIdx.x * 256 + threadIdx.x;
    if (e < N_EDGES) atomicAdd(&ideg[ei[N_EDGES + e]], 1);
}

// ---------------- parallel scan, phase 1: per-block sums (1024 elems/block) ----------------
__global__ __launch_bounds__(256) void scan_part(const int* __restrict__ ideg, int* __restrict__ bsum) {
    __shared__ int red[256];
    int b = blockIdx.x, tid = threadIdx.x;
    int base = b * 1024 + tid * 4;
    int s = 0;
#pragma unroll
    for (int i = 0; i < 4; i++) s += (base + i < N_NODES) ? ideg[base + i] : 0;
    red[tid] = s;
    __syncthreads();
    for (int off = 128; off > 0; off >>= 1) {
        if (tid < off) red[tid] += red[tid + off];
        __syncthreads();
    }
    if (tid == 0) bsum[b] = red[0];
}

// ---------------- phase 2: exclusive scan of the 98 block sums ----------------
__global__ __launch_bounds__(128) void scan_block(int* __restrict__ bsum) {
    __shared__ int tmp[128];
    int tid = threadIdx.x;
    int v = (tid < NBLK) ? bsum[tid] : 0;
    tmp[tid] = v;
    __syncthreads();
    int acc = v;
    for (int off = 1; off < 128; off <<= 1) {
        int t = (tid >= off) ? tmp[tid - off] : 0;
        __syncthreads();
        tmp[tid] = acc = acc + t;
        __syncthreads();
    }
    if (tid < NBLK) bsum[tid] = acc - v;   // exclusive
}

// ---------------- phase 3: local scan + global offset -> rowptr, cursor ----------------
__global__ __launch_bounds__(256) void scan_final(const int* __restrict__ ideg, const int* __restrict__ bsum,
                                                  int* __restrict__ rowptr, int* __restrict__ cursor) {
    __shared__ int tsum[256];
    int b = blockIdx.x, tid = threadIdx.x;
    int base = b * 1024 + tid * 4;
    int v[4];
#pragma unroll
    for (int i = 0; i < 4; i++) v[i] = (base + i < N_NODES) ? ideg[base + i] : 0;
    int s = v[0] + v[1] + v[2] + v[3];
    tsum[tid] = s;
    __syncthreads();
    int acc = s;
    for (int off = 1; off < 256; off <<= 1) {
        int t = (tid >= off) ? tsum[tid - off] : 0;
        __syncthreads();
        tsum[tid] = acc = acc + t;
        __syncthreads();
    }
    int off = bsum[b] + acc - s;
#pragma unroll
    for (int i = 0; i < 4; i++) {
        if (base + i < N_NODES) { rowptr[base + i] = off; cursor[base + i] = off; off += v[i]; }
    }
    if (b == 0 && tid == 0) rowptr[N_NODES] = N_EDGES;
}

// ---------------- fill CSR src list ----------------
__global__ __launch_bounds__(256) void fill_kernel(const int* __restrict__ ei, int* __restrict__ cursor,
                                                   int* __restrict__ esrc) {
    int e = blockIdx.x * 256 + threadIdx.x;
    if (e < N_EDGES) {
        int dd = ei[N_EDGES + e];
        int pos = atomicAdd(&cursor[dd], 1);
        esrc[pos] = ei[e];
    }
}

// ---------------- layer 1 fused: float4 gather (32 edges/instr) + linears ----------------
__global__ __launch_bounds__(256) void layer1_fused(const float* __restrict__ x, const int* __restrict__ rowptr,
                                                    const int* __restrict__ esrc,
                                                    const float* __restrict__ Wl, const float* __restrict__ b,
                                                    const float* __restrict__ Wr, float* __restrict__ out) {
    __shared__ float sa[4][8], sx[4][8];
    int tid = threadIdx.x;
    int sub = tid >> 6, lane = tid & 63;
    int j = lane >> 1, half = lane & 1;        // 32 edges x 2 float4-halves
    int n = blockIdx.x * 4 + sub;
    int r0 = __builtin_amdgcn_readfirstlane(rowptr[n]);
    int r1 = __builtin_amdgcn_readfirstlane(rowptr[n + 1]);
    const float4* x4 = (const float4*)x;
    float ax = 0.f, ay = 0.f, az = 0.f, aw = 0.f;
    for (int e = r0; e < r1; e += 32) {
        int idx = e + j;
        if (idx < r1) {
            int s = esrc[idx];
            float4 v = x4[(size_t)s * 2 + half];
            ax += v.x; ay += v.y; az += v.z; aw += v.w;
        }
    }
#pragma unroll
    for (int m = 2; m <= 32; m <<= 1) {
        ax += __shfl_xor(ax, m); ay += __shfl_xor(ay, m);
        az += __shfl_xor(az, m); aw += __shfl_xor(aw, m);
    }
    float invn = 1.0f / fmaxf((float)(r1 - r0), 1.0f);
    if (lane < 2) {
        float4 xs = x4[(size_t)n * 2 + lane];
        float4 av; av.x = ax * invn; av.y = ay * invn; av.z = az * invn; av.w = aw * invn;
        ((float4*)sa[sub])[lane] = av;
        ((float4*)sx[sub])[lane] = xs;
    }
    __syncthreads();
    float al = 0.f, ar = 0.f;
#pragma unroll
    for (int kk = 0; kk < 8; kk++) {
        al += sa[sub][kk] * Wl[kk * 64 + lane];
        ar += sx[sub][kk] * Wr[kk * 64 + lane];
    }
    out[(size_t)n * 64 + lane] = fmaxf(al + b[lane] + ar, 0.0f);
}

// ---------------- layers 2/3: float4 gather (4 edges/instr, 20 in flight) + linears (+pool) ----------------
template <bool RELU, bool POOL>
__global__ __launch_bounds__(256) void layerN_fused(const float* __restrict__ h, const int* __restrict__ rowptr,
                                                    const int* __restrict__ esrc,
                                                    const float* __restrict__ Wl, const float* __restrict__ b,
                                                    const float* __restrict__ Wr, float* __restrict__ out,
                                                    const int* __restrict__ batch, float* __restrict__ g) {
    __shared__ float sh[4][64], sa[4][64];
    __shared__ int sbat[4];
    int tid = threadIdx.x;
    int sub = tid >> 6, lane = tid & 63;
    int grp = lane >> 4, q = lane & 15;        // 4 edge-groups x 16 float4-lanes
    int n = blockIdx.x * 4 + sub;
    int r0 = __builtin_amdgcn_readfirstlane(rowptr[n]);
    int r1 = __builtin_amdgcn_readfirstlane(rowptr[n + 1]);
    const float4* h4 = (const float4*)h;
    float self = h[(size_t)n * 64 + lane];
    // 5 chunks = 20 edges in flight (covers ~97% of Poisson-12 degrees)
    float4 vv[5];
#pragma unroll
    for (int c = 0; c < 5; c++) {
        vv[c].x = 0.f; vv[c].y = 0.f; vv[c].z = 0.f; vv[c].w = 0.f;
        int idx = r0 + 4 * c + grp;
        if (idx < r1) {
            int s = esrc[idx];
            vv[c] = h4[(size_t)s * 16 + q];
        }
    }
    float ax = 0.f, ay = 0.f, az = 0.f, aw = 0.f;
#pragma unroll
    for (int c = 0; c < 5; c++) { ax += vv[c].x; ay += vv[c].y; az += vv[c].z; aw += vv[c].w; }
    // rare tail (deg > 20)
    for (int e = r0 + 20; e < r1; e += 4) {
        int idx = e + grp;
        if (idx < r1) {
            int s = esrc[idx];
            float4 v = h4[(size_t)s * 16 + q];
            ax += v.x; ay += v.y; az += v.z; aw += v.w;
        }
    }
    ax += __shfl_xor(ax, 16); ay += __shfl_xor(ay, 16); az += __shfl_xor(az, 16); aw += __shfl_xor(aw, 16);
    ax += __shfl_xor(ax, 32); ay += __shfl_xor(ay, 32); az += __shfl_xor(az, 32); aw += __shfl_xor(aw, 32);
    float invn = 1.0f / fmaxf((float)(r1 - r0), 1.0f);
    sh[sub][lane] = self;
    if (grp == 0) {
        float4 av; av.x = ax * invn; av.y = ay * invn; av.z = az * invn; av.w = aw * invn;
        ((float4*)sa[sub])[q] = av;
    }
    if (POOL && lane == 0) sbat[sub] = batch[n];
    __syncthreads();
    float al = 0.f, ar = 0.f;
#pragma unroll 8
    for (int k = 0; k < 64; k++) {
        al += sa[sub][k] * Wl[k * 64 + lane];
        ar += sh[sub][k] * Wr[k * 64 + lane];
    }
    float v = al + b[lane] + ar;
    if (RELU) v = fmaxf(v, 0.0f);
    if (!POOL) {
        out[(size_t)n * 64 + lane] = v;
    } else {
        sa[sub][lane] = v;             // wave-synchronous overwrite of own row: safe
        __syncthreads();
        if (sub == 0) {                // batch is sorted: block covers 1..4 graphs
            int b0 = sbat[0], b3 = sbat[3];
            if (b0 == b3) {
                float s = sa[0][lane] + sa[1][lane] + sa[2][lane] + sa[3][lane];
                atomicAdd(&g[b0 * 64 + lane], s);
            } else {
                float acc = sa[0][lane]; int cur = b0;
#pragma unroll
                for (int i = 1; i < 4; i++) {
                    int bi = sbat[i];
                    if (bi != cur) { atomicAdd(&g[cur * 64 + lane], acc); cur = bi; acc = 0.f; }
                    acc += sa[i][lane];
                }
                atomicAdd(&g[cur * 64 + lane], acc);
            }
        }
    }
}

// ---------------- head: one wave per graph, 64 blocks x 4 waves ----------------
__global__ __launch_bounds__(256) void head_kernel(const float* __restrict__ g, const float* __restrict__ Wc1,
                                                   const float* __restrict__ bc1, const float* __restrict__ Wc2,
                                                   const float* __restrict__ bc2, float* __restrict__ out) {
    __shared__ float sg[4][64];
    int tid = threadIdx.x, sub = tid >> 6, lane = tid & 63;
    int gid = blockIdx.x * 4 + sub;
    sg[sub][lane] = g[gid * 64 + lane];
    __syncthreads();
    int j = lane & 31, kh = lane >> 5;
    float a = 0.f;
#pragma unroll
    for (int kk = 0; kk < 32; kk++) {
        int k = kh * 32 + kk;
        a += sg[sub][k] * Wc1[k * 32 + j];
    }
    a += __shfl_xor(a, 32);
    float contrib = (lane < 32) ? fmaxf(a + bc1[j], 0.0f) * Wc2[j] : 0.0f;
    contrib += __shfl_xor(contrib, 16);
    contrib += __shfl_xor(contrib, 8);
    contrib += __shfl_xor(contrib, 4);
    contrib += __shfl_xor(contrib, 2);
    contrib += __shfl_xor(contrib, 1);
    if (lane == 0) out[gid] = contrib + bc2[0];
}

extern "C" void kernel_launch(void* const* d_in, const int* in_sizes, int n_in,
                              void* d_out, int out_size, void* d_ws, size_t ws_size,
                              hipStream_t stream) {
    const float* x   = (const float*)d_in[0];
    const int*   ei  = (const int*)d_in[1];
    const int*   bat = (const int*)d_in[2];
    const float* W1l = (const float*)d_in[3];
    const float* b1  = (const float*)d_in[4];
    const float* W1r = (const float*)d_in[5];
    const float* W2l = (const float*)d_in[6];
    const float* b2  = (const float*)d_in[7];
    const float* W2r = (const float*)d_in[8];
    const float* W3l = (const float*)d_in[9];
    const float* b3  = (const float*)d_in[10];
    const float* W3r = (const float*)d_in[11];
    const float* Wc1 = (const float*)d_in[12];
    const float* bc1 = (const float*)d_in[13];
    const float* Wc2 = (const float*)d_in[14];
    const float* bc2 = (const float*)d_in[15];

    float* ws = (float*)d_ws;
    int*   rowptr = (int*)(ws);                 // 100001 used, pad to 100352
    int*   bsum   = (int*)(ws) + 100096;        // 98 ints in rowptr's pad
    int*   esrc   = (int*)(ws + 100352);        // 1200000 (pad 1200128)
    float* g      = ws + 1300480;               // 16384
    float* bufA   = ws + 1316864;               // 6400000
    float* bufB   = ws + 7716864;               // 6400000
    int*   ideg   = (int*)bufA;                 // alias: dead before layer1 writes bufA
    int*   cursor = (int*)bufB;                 // alias: dead before layer2 writes bufB

    hipMemsetAsync(ideg, 0, (size_t)N_NODES * 4, stream);
    hipMemsetAsync(g,    0, (size_t)N_GRAPHS * 64 * 4, stream);

    hist_kernel<<<(N_EDGES + 255) / 256, 256, 0, stream>>>(ei, ideg);
    scan_part<<<NBLK, 256, 0, stream>>>(ideg, bsum);
    scan_block<<<1, 128, 0, stream>>>(bsum);
    scan_final<<<NBLK, 256, 0, stream>>>(ideg, bsum, rowptr, cursor);
    fill_kernel<<<(N_EDGES + 255) / 256, 256, 0, stream>>>(ei, cursor, esrc);

    layer1_fused<<<N_NODES / 4, 256, 0, stream>>>(x, rowptr, esrc, W1l, b1, W1r, bufA);
    layerN_fused<true,  false><<<N_NODES / 4, 256, 0, stream>>>(bufA, rowptr, esrc, W2l, b2, W2r, bufB,
                                                                nullptr, nullptr);
    layerN_fused<false, true ><<<N_NODES / 4, 256, 0, stream>>>(bufB, rowptr, esrc, W3l, b3, W3r, nullptr,
                                                                bat, g);
    head_kernel<<<N_GRAPHS / 4, 256, 0, stream>>>(g, Wc1, bc1, Wc2, bc2, (float*)d_out);
}

// Round 6
// 498.229 us; speedup vs baseline: 2.1462x; 1.0227x over previous
//
#include <hip/hip_runtime.h>

#define N_NODES 100000
#define N_EDGES 1200000
#define N_GRAPHS 256
#define NBLK 98              // ceil(100000/1024)

// ---- bf16 helpers (fp32 <-> bf16 as ushort, RNE) ----
__device__ inline unsigned short f2b(float f) {
    union { float f; unsigned u; } c; c.f = f;
    unsigned u = c.u;
    u += 0x7fff + ((u >> 16) & 1);
    return (unsigned short)(u >> 16);
}
__device__ inline float blo(unsigned u) { union { unsigned i; float f; } c; c.i = u << 16; return c.f; }
__device__ inline float bhi(unsigned u) { union { unsigned i; float f; } c; c.i = u & 0xffff0000u; return c.f; }
__device__ inline float b2f(unsigned short h) { union { unsigned i; float f; } c; c.i = ((unsigned)h) << 16; return c.f; }

// ---------------- degree histogram (int atomics) ----------------
__global__ __launch_bounds__(256) void hist_kernel(const int* __restrict__ ei, int* __restrict__ ideg) {
    int e = blockIdx.x * 256 + threadIdx.x;
    if (e < N_EDGES) atomicAdd(&ideg[ei[N_EDGES + e]], 1);
}

// ---------------- parallel scan, phase 1 ----------------
__global__ __launch_bounds__(256) void scan_part(const int* __restrict__ ideg, int* __restrict__ bsum) {
    __shared__ int red[256];
    int b = blockIdx.x, tid = threadIdx.x;
    int base = b * 1024 + tid * 4;
    int s = 0;
#pragma unroll
    for (int i = 0; i < 4; i++) s += (base + i < N_NODES) ? ideg[base + i] : 0;
    red[tid] = s;
    __syncthreads();
    for (int off = 128; off > 0; off >>= 1) {
        if (tid < off) red[tid] += red[tid + off];
        __syncthreads();
    }
    if (tid == 0) bsum[b] = red[0];
}

// ---------------- phase 2 ----------------
__global__ __launch_bounds__(128) void scan_block(int* __restrict__ bsum) {
    __shared__ int tmp[128];
    int tid = threadIdx.x;
    int v = (tid < NBLK) ? bsum[tid] : 0;
    tmp[tid] = v;
    __syncthreads();
    int acc = v;
    for (int off = 1; off < 128; off <<= 1) {
        int t = (tid >= off) ? tmp[tid - off] : 0;
        __syncthreads();
        tmp[tid] = acc = acc + t;
        __syncthreads();
    }
    if (tid < NBLK) bsum[tid] = acc - v;   // exclusive
}

// ---------------- phase 3 ----------------
__global__ __launch_bounds__(256) void scan_final(const int* __restrict__ ideg, const int* __restrict__ bsum,
                                                  int* __restrict__ rowptr, int* __restrict__ cursor) {
    __shared__ int tsum[256];
    int b = blockIdx.x, tid = threadIdx.x;
    int base = b * 1024 + tid * 4;
    int v[4];
#pragma unroll
    for (int i = 0; i < 4; i++) v[i] = (base + i < N_NODES) ? ideg[base + i] : 0;
    int s = v[0] + v[1] + v[2] + v[3];
    tsum[tid] = s;
    __syncthreads();
    int acc = s;
    for (int off = 1; off < 256; off <<= 1) {
        int t = (tid >= off) ? tsum[tid - off] : 0;
        __syncthreads();
        tsum[tid] = acc = acc + t;
        __syncthreads();
    }
    int off = bsum[b] + acc - s;
#pragma unroll
    for (int i = 0; i < 4; i++) {
        if (base + i < N_NODES) { rowptr[base + i] = off; cursor[base + i] = off; off += v[i]; }
    }
    if (b == 0 && tid == 0) rowptr[N_NODES] = N_EDGES;
}

// ---------------- fill CSR src list; store BYTE OFFSET (src*128) ----------------
__global__ __launch_bounds__(256) void fill_kernel(const int* __restrict__ ei, int* __restrict__ cursor,
                                                   int* __restrict__ esrc) {
    int e = blockIdx.x * 256 + threadIdx.x;
    if (e < N_EDGES) {
        int dd = ei[N_EDGES + e];
        int pos = atomicAdd(&cursor[dd], 1);
        esrc[pos] = ei[e] << 7;            // src * 128 (bf16 row bytes)
    }
}

// ---------------- layer 1: fp32 x gather (32 edges/instr) -> bf16 out ----------------
__global__ __launch_bounds__(256) void layer1_fused(const float* __restrict__ x, const int* __restrict__ rowptr,
                                                    const int* __restrict__ esrc,
                                                    const float* __restrict__ Wl, const float* __restrict__ b,
                                                    const float* __restrict__ Wr, unsigned short* __restrict__ ob) {
    __shared__ float sa[4][8], sx[4][8];
    int tid = threadIdx.x;
    int sub = tid >> 6, lane = tid & 63;
    int j = lane >> 1, half = lane & 1;        // 32 edges x 2 float4-halves
    int n = blockIdx.x * 4 + sub;
    int r0 = __builtin_amdgcn_readfirstlane(rowptr[n]);
    int r1 = __builtin_amdgcn_readfirstlane(rowptr[n + 1]);
    const float4* x4 = (const float4*)x;
    float ax = 0.f, ay = 0.f, az = 0.f, aw = 0.f;
    for (int e = r0; e < r1; e += 32) {
        int idx = e + j;
        if (idx < r1) {
            int off = esrc[idx];               // src*128; x row = 32 B -> x4 index = off>>6
            float4 v = x4[(off >> 6) + half];
            ax += v.x; ay += v.y; az += v.z; aw += v.w;
        }
    }
#pragma unroll
    for (int m = 2; m <= 32; m <<= 1) {
        ax += __shfl_xor(ax, m); ay += __shfl_xor(ay, m);
        az += __shfl_xor(az, m); aw += __shfl_xor(aw, m);
    }
    float invn = 1.0f / fmaxf((float)(r1 - r0), 1.0f);
    if (lane < 2) {
        float4 xs = x4[(size_t)n * 2 + lane];
        float4 av; av.x = ax * invn; av.y = ay * invn; av.z = az * invn; av.w = aw * invn;
        ((float4*)sa[sub])[lane] = av;
        ((float4*)sx[sub])[lane] = xs;
    }
    __syncthreads();
    float al = 0.f, ar = 0.f;
#pragma unroll
    for (int kk = 0; kk < 8; kk++) {
        al += sa[sub][kk] * Wl[kk * 64 + lane];
        ar += sx[sub][kk] * Wr[kk * 64 + lane];
    }
    ob[(size_t)n * 64 + lane] = f2b(fmaxf(al + b[lane] + ar, 0.0f));
}

// ---------------- layers 2/3: bf16 gather (8 edges/instr, 24 in flight) ----------------
template <bool RELU, bool POOL>
__global__ __launch_bounds__(256) void layerN_fused(const unsigned short* __restrict__ hb,
                                                    const int* __restrict__ rowptr,
                                                    const int* __restrict__ esrc,
                                                    const float* __restrict__ Wl, const float* __restrict__ b,
                                                    const float* __restrict__ Wr, unsigned short* __restrict__ ob,
                                                    const int* __restrict__ batch, float* __restrict__ g) {
    __shared__ float sh[4][64], sa[4][64];
    __shared__ int sbat[4];
    int tid = threadIdx.x;
    int sub = tid >> 6, lane = tid & 63;
    int grp = lane >> 3, q = lane & 7;         // 8 edge-groups x 8 uint4-lanes (16 B each)
    int n = blockIdx.x * 4 + sub;
    int r0 = __builtin_amdgcn_readfirstlane(rowptr[n]);
    int r1 = __builtin_amdgcn_readfirstlane(rowptr[n + 1]);
    const uint4* h16 = (const uint4*)hb;       // row = 8 x uint4
    float self = b2f(hb[(size_t)n * 64 + lane]);
    // 3 chunks = 24 edges in flight (covers ~99.9% of Poisson-12 degrees)
    uint4 v[3];
#pragma unroll
    for (int c = 0; c < 3; c++) {
        uint4 vv; vv.x = 0u; vv.y = 0u; vv.z = 0u; vv.w = 0u;
        int idx = r0 + 8 * c + grp;
        if (idx < r1) {
            int off = esrc[idx];               // src*128; uint4 index = off>>4
            vv = h16[(off >> 4) + q];
        }
        v[c] = vv;
    }
    float a[8];
#pragma unroll
    for (int j = 0; j < 8; j++) a[j] = 0.f;
#pragma unroll
    for (int c = 0; c < 3; c++) {
        a[0] += blo(v[c].x); a[1] += bhi(v[c].x);
        a[2] += blo(v[c].y); a[3] += bhi(v[c].y);
        a[4] += blo(v[c].z); a[5] += bhi(v[c].z);
        a[6] += blo(v[c].w); a[7] += bhi(v[c].w);
    }
    // rare tail (deg > 24)
    for (int e = r0 + 24; e < r1; e += 8) {
        int idx = e + grp;
        if (idx < r1) {
            int off = esrc[idx];
            uint4 vv = h16[(off >> 4) + q];
            a[0] += blo(vv.x); a[1] += bhi(vv.x);
            a[2] += blo(vv.y); a[3] += bhi(vv.y);
            a[4] += blo(vv.z); a[5] += bhi(vv.z);
            a[6] += blo(vv.w); a[7] += bhi(vv.w);
        }
    }
    // reduce over the 8 edge-groups
#pragma unroll
    for (int j = 0; j < 8; j++) {
        a[j] += __shfl_xor(a[j], 8);
        a[j] += __shfl_xor(a[j], 16);
        a[j] += __shfl_xor(a[j], 32);
    }
    float invn = 1.0f / fmaxf((float)(r1 - r0), 1.0f);
    sh[sub][lane] = self;
    if (grp == 0) {
#pragma unroll
        for (int j = 0; j < 8; j++) sa[sub][q * 8 + j] = a[j] * invn;
    }
    if (POOL && lane == 0) sbat[sub] = batch[n];
    __syncthreads();
    float al = 0.f, ar = 0.f;
#pragma unroll 8
    for (int k = 0; k < 64; k++) {
        al += sa[sub][k] * Wl[k * 64 + lane];
        ar += sh[sub][k] * Wr[k * 64 + lane];
    }
    float vv = al + b[lane] + ar;
    if (RELU) vv = fmaxf(vv, 0.0f);
    if (!POOL) {
        ob[(size_t)n * 64 + lane] = f2b(vv);
    } else {
        sa[sub][lane] = vv;            // wave-synchronous overwrite of own row: safe
        __syncthreads();
        if (sub == 0) {                // batch is sorted: block covers 1..4 graphs
            int b0 = sbat[0], b3 = sbat[3];
            if (b0 == b3) {
                float s = sa[0][lane] + sa[1][lane] + sa[2][lane] + sa[3][lane];
                atomicAdd(&g[b0 * 64 + lane], s);
            } else {
                float acc = sa[0][lane]; int cur = b0;
#pragma unroll
                for (int i = 1; i < 4; i++) {
                    int bi = sbat[i];
                    if (bi != cur) { atomicAdd(&g[cur * 64 + lane], acc); cur = bi; acc = 0.f; }
                    acc += sa[i][lane];
                }
                atomicAdd(&g[cur * 64 + lane], acc);
            }
        }
    }
}

// ---------------- head: one wave per graph ----------------
__global__ __launch_bounds__(256) void head_kernel(const float* __restrict__ g, const float* __restrict__ Wc1,
                                                   const float* __restrict__ bc1, const float* __restrict__ Wc2,
                                                   const float* __restrict__ bc2, float* __restrict__ out) {
    __shared__ float sg[4][64];
    int tid = threadIdx.x, sub = tid >> 6, lane = tid & 63;
    int gid = blockIdx.x * 4 + sub;
    sg[sub][lane] = g[gid * 64 + lane];
    __syncthreads();
    int j = lane & 31, kh = lane >> 5;
    float a = 0.f;
#pragma unroll
    for (int kk = 0; kk < 32; kk++) {
        int k = kh * 32 + kk;
        a += sg[sub][k] * Wc1[k * 32 + j];
    }
    a += __shfl_xor(a, 32);
    float contrib = (lane < 32) ? fmaxf(a + bc1[j], 0.0f) * Wc2[j] : 0.0f;
    contrib += __shfl_xor(contrib, 16);
    contrib += __shfl_xor(contrib, 8);
    contrib += __shfl_xor(contrib, 4);
    contrib += __shfl_xor(contrib, 2);
    contrib += __shfl_xor(contrib, 1);
    if (lane == 0) out[gid] = contrib + bc2[0];
}

extern "C" void kernel_launch(void* const* d_in, const int* in_sizes, int n_in,
                              void* d_out, int out_size, void* d_ws, size_t ws_size,
                              hipStream_t stream) {
    const float* x   = (const float*)d_in[0];
    const int*   ei  = (const int*)d_in[1];
    const int*   bat = (const int*)d_in[2];
    const float* W1l = (const float*)d_in[3];
    const float* b1  = (const float*)d_in[4];
    const float* W1r = (const float*)d_in[5];
    const float* W2l = (const float*)d_in[6];
    const float* b2  = (const float*)d_in[7];
    const float* W2r = (const float*)d_in[8];
    const float* W3l = (const float*)d_in[9];
    const float* b3  = (const float*)d_in[10];
    const float* W3r = (const float*)d_in[11];
    const float* Wc1 = (const float*)d_in[12];
    const float* bc1 = (const float*)d_in[13];
    const float* Wc2 = (const float*)d_in[14];
    const float* bc2 = (const float*)d_in[15];

    float* ws = (float*)d_ws;
    int*    rowptr = (int*)(ws);                 // 100001 used, pad to 100352
    int*    bsum   = (int*)(ws) + 100096;        // 98 ints in rowptr's pad
    int*    esrc   = (int*)(ws + 100352);        // 1200000 byte-offsets (pad 1200128)
    float*  g      = ws + 1300480;               // 16384
    unsigned short* hb1 = (unsigned short*)(ws + 1316864);  // N*64 bf16 = 3.2M floats worth
    unsigned short* hb2 = (unsigned short*)(ws + 4516864);  // N*64 bf16
    int*    ideg   = (int*)hb1;                  // alias: dead before layer1 writes hb1
    int*    cursor = (int*)hb2;                  // alias: dead before layer2 writes hb2

    hipMemsetAsync(ideg, 0, (size_t)N_NODES * 4, stream);
    hipMemsetAsync(g,    0, (size_t)N_GRAPHS * 64 * 4, stream);

    hist_kernel<<<(N_EDGES + 255) / 256, 256, 0, stream>>>(ei, ideg);
    scan_part<<<NBLK, 256, 0, stream>>>(ideg, bsum);
    scan_block<<<1, 128, 0, stream>>>(bsum);
    scan_final<<<NBLK, 256, 0, stream>>>(ideg, bsum, rowptr, cursor);
    fill_kernel<<<(N_EDGES + 255) / 256, 256, 0, stream>>>(ei, cursor, esrc);

    layer1_fused<<<N_NODES / 4, 256, 0, stream>>>(x, rowptr, esrc, W1l, b1, W1r, hb1);
    layerN_fused<true,  false><<<N_NODES / 4, 256, 0, stream>>>(hb1, rowptr, esrc, W2l, b2, W2r, hb2,
                                                                nullptr, nullptr);
    layerN_fused<false, true ><<<N_NODES / 4, 256, 0, stream>>>(hb2, rowptr, esrc, W3l, b3, W3r, nullptr,
                                                                bat, g);
    head_kernel<<<N_GRAPHS / 4, 256, 0, stream>>>(g, Wc1, bc1, Wc2, bc2, (float*)d_out);
}

// Round 8
// 410.733 us; speedup vs baseline: 2.6034x; 1.2130x over previous
//
#include <hip/hip_runtime.h>

#define N_NODES 100000
#define N_EDGES 1200000
#define N_GRAPHS 256
#define NBLK 98              // ceil(100000/1024)

typedef __attribute__((ext_vector_type(8))) short bf16x8;
typedef __attribute__((ext_vector_type(4))) float f32x4;

// ---- bf16 helpers (fp32 <-> bf16 as ushort, RNE) ----
__device__ inline unsigned short f2b(float f) {
    union { float f; unsigned u; } c; c.f = f;
    unsigned u = c.u;
    u += 0x7fff + ((u >> 16) & 1);
    return (unsigned short)(u >> 16);
}
__device__ inline float blo(unsigned u) { union { unsigned i; float f; } c; c.i = u << 16; return c.f; }
__device__ inline float bhi(unsigned u) { union { unsigned i; float f; } c; c.i = u & 0xffff0000u; return c.f; }
__device__ inline float b2f(unsigned short h) { union { unsigned i; float f; } c; c.i = ((unsigned)h) << 16; return c.f; }

// ---------------- degree histogram (int atomics) ----------------
__global__ __launch_bounds__(256) void hist_kernel(const int* __restrict__ ei, int* __restrict__ ideg) {
    int e = blockIdx.x * 256 + threadIdx.x;
    if (e < N_EDGES) atomicAdd(&ideg[ei[N_EDGES + e]], 1);
}

// ---------------- parallel scan, phase 1 ----------------
__global__ __launch_bounds__(256) void scan_part(const int* __restrict__ ideg, int* __restrict__ bsum) {
    __shared__ int red[256];
    int b = blockIdx.x, tid = threadIdx.x;
    int base = b * 1024 + tid * 4;
    int s = 0;
#pragma unroll
    for (int i = 0; i < 4; i++) s += (base + i < N_NODES) ? ideg[base + i] : 0;
    red[tid] = s;
    __syncthreads();
    for (int off = 128; off > 0; off >>= 1) {
        if (tid < off) red[tid] += red[tid + off];
        __syncthreads();
    }
    if (tid == 0) bsum[b] = red[0];
}

// ---------------- phase 2 ----------------
__global__ __launch_bounds__(128) void scan_block(int* __restrict__ bsum) {
    __shared__ int tmp[128];
    int tid = threadIdx.x;
    int v = (tid < NBLK) ? bsum[tid] : 0;
    tmp[tid] = v;
    __syncthreads();
    int acc = v;
    for (int off = 1; off < 128; off <<= 1) {
        int t = (tid >= off) ? tmp[tid - off] : 0;
        __syncthreads();
        tmp[tid] = acc = acc + t;
        __syncthreads();
    }
    if (tid < NBLK) bsum[tid] = acc - v;   // exclusive
}

// ---------------- phase 3 ----------------
__global__ __launch_bounds__(256) void scan_final(const int* __restrict__ ideg, const int* __restrict__ bsum,
                                                  int* __restrict__ rowptr, int* __restrict__ cursor) {
    __shared__ int tsum[256];
    int b = blockIdx.x, tid = threadIdx.x;
    int base = b * 1024 + tid * 4;
    int v[4];
#pragma unroll
    for (int i = 0; i < 4; i++) v[i] = (base + i < N_NODES) ? ideg[base + i] : 0;
    int s = v[0] + v[1] + v[2] + v[3];
    tsum[tid] = s;
    __syncthreads();
    int acc = s;
    for (int off = 1; off < 256; off <<= 1) {
        int t = (tid >= off) ? tsum[tid - off] : 0;
        __syncthreads();
        tsum[tid] = acc = acc + t;
        __syncthreads();
    }
    int off = bsum[b] + acc - s;
#pragma unroll
    for (int i = 0; i < 4; i++) {
        if (base + i < N_NODES) { rowptr[base + i] = off; cursor[base + i] = off; off += v[i]; }
    }
    if (b == 0 && tid == 0) rowptr[N_NODES] = N_EDGES;
}

// ---------------- fill CSR src list; store BYTE OFFSET (src*128) ----------------
__global__ __launch_bounds__(256) void fill_kernel(const int* __restrict__ ei, int* __restrict__ cursor,
                                                   int* __restrict__ esrc) {
    int e = blockIdx.x * 256 + threadIdx.x;
    if (e < N_EDGES) {
        int dd = ei[N_EDGES + e];
        int pos = atomicAdd(&cursor[dd], 1);
        esrc[pos] = ei[e] << 7;            // src * 128 (bf16 row bytes)
    }
}

// ---------------- prepack W' = [Wl;Wr] (128x64) into MFMA B-fragment order, bf16 ----------------
// layout: idx = s*2048 + t*512 + lane*8 + j  <->  W'[k = s*32 + (lane>>4)*8 + j][n = t*16 + (lane&15)]
__global__ __launch_bounds__(256) void prepack_kernel(const float* __restrict__ W2l, const float* __restrict__ W2r,
                                                      const float* __restrict__ W3l, const float* __restrict__ W3r,
                                                      unsigned short* __restrict__ pw2, unsigned short* __restrict__ pw3) {
    int id = blockIdx.x * 256 + threadIdx.x;   // 16384 total
    int layer = id >> 13;
    int r = id & 8191;
    int j = r & 7, lane = (r >> 3) & 63, t = (r >> 9) & 3, s = (r >> 11) & 3;
    int k = s * 32 + (lane >> 4) * 8 + j;
    int n = t * 16 + (lane & 15);
    const float* Wl = layer ? W3l : W2l;
    const float* Wr = layer ? W3r : W2r;
    float v = (k < 64) ? Wl[k * 64 + n] : Wr[(k - 64) * 64 + n];
    unsigned short* dst = layer ? pw3 : pw2;
    dst[r] = f2b(v);
}

// ---------------- layer 1: fp32 x gather (32 edges/instr) -> bf16 out ----------------
__global__ __launch_bounds__(256) void layer1_fused(const float* __restrict__ x, const int* __restrict__ rowptr,
                                                    const int* __restrict__ esrc,
                                                    const float* __restrict__ Wl, const float* __restrict__ b,
                                                    const float* __restrict__ Wr, unsigned short* __restrict__ ob) {
    __shared__ float sa[4][8], sx[4][8];
    int tid = threadIdx.x;
    int sub = tid >> 6, lane = tid & 63;
    int j = lane >> 1, half = lane & 1;        // 32 edges x 2 float4-halves
    int n = blockIdx.x * 4 + sub;
    int r0 = __builtin_amdgcn_readfirstlane(rowptr[n]);
    int r1 = __builtin_amdgcn_readfirstlane(rowptr[n + 1]);
    const float4* x4 = (const float4*)x;
    float ax = 0.f, ay = 0.f, az = 0.f, aw = 0.f;
    for (int e = r0; e < r1; e += 32) {
        int idx = e + j;
        if (idx < r1) {
            int off = esrc[idx];               // src*128; x row = 32 B -> x4 index = off>>6
            float4 v = x4[(off >> 6) + half];
            ax += v.x; ay += v.y; az += v.z; aw += v.w;
        }
    }
#pragma unroll
    for (int m = 2; m <= 32; m <<= 1) {
        ax += __shfl_xor(ax, m); ay += __shfl_xor(ay, m);
        az += __shfl_xor(az, m); aw += __shfl_xor(aw, m);
    }
    float invn = 1.0f / fmaxf((float)(r1 - r0), 1.0f);
    if (lane < 2) {
        float4 xs = x4[(size_t)n * 2 + lane];
        float4 av; av.x = ax * invn; av.y = ay * invn; av.z = az * invn; av.w = aw * invn;
        ((float4*)sa[sub])[lane] = av;
        ((float4*)sx[sub])[lane] = xs;
    }
    __syncthreads();
    float al = 0.f, ar = 0.f;
#pragma unroll
    for (int kk = 0; kk < 8; kk++) {
        al += sa[sub][kk] * Wl[kk * 64 + lane];
        ar += sx[sub][kk] * Wr[kk * 64 + lane];
    }
    ob[(size_t)n * 64 + lane] = f2b(fmaxf(al + b[lane] + ar, 0.0f));
}

// ---------------- gather-mean only: bf16 rows, 8 edges/instr, 24 in flight, no LDS ----------------
__global__ __launch_bounds__(256) void agg_kernel(const unsigned short* __restrict__ hb,
                                                  const int* __restrict__ rowptr,
                                                  const int* __restrict__ esrc,
                                                  unsigned short* __restrict__ aggb) {
    int tid = threadIdx.x;
    int sub = tid >> 6, lane = tid & 63;
    int grp = lane >> 3, q = lane & 7;         // 8 edge-groups x 8 uint4-lanes (16 B each)
    int n = blockIdx.x * 4 + sub;
    int r0 = __builtin_amdgcn_readfirstlane(rowptr[n]);
    int r1 = __builtin_amdgcn_readfirstlane(rowptr[n + 1]);
    const uint4* h16 = (const uint4*)hb;
    uint4 v[3];
#pragma unroll
    for (int c = 0; c < 3; c++) {
        uint4 vv; vv.x = 0u; vv.y = 0u; vv.z = 0u; vv.w = 0u;
        int idx = r0 + 8 * c + grp;
        if (idx < r1) {
            int off = esrc[idx];
            vv = h16[(off >> 4) + q];
        }
        v[c] = vv;
    }
    float a[8];
#pragma unroll
    for (int j = 0; j < 8; j++) a[j] = 0.f;
#pragma unroll
    for (int c = 0; c < 3; c++) {
        a[0] += blo(v[c].x); a[1] += bhi(v[c].x);
        a[2] += blo(v[c].y); a[3] += bhi(v[c].y);
        a[4] += blo(v[c].z); a[5] += bhi(v[c].z);
        a[6] += blo(v[c].w); a[7] += bhi(v[c].w);
    }
    for (int e = r0 + 24; e < r1; e += 8) {    // rare tail (deg > 24)
        int idx = e + grp;
        if (idx < r1) {
            int off = esrc[idx];
            uint4 vv = h16[(off >> 4) + q];
            a[0] += blo(vv.x); a[1] += bhi(vv.x);
            a[2] += blo(vv.y); a[3] += bhi(vv.y);
            a[4] += blo(vv.z); a[5] += bhi(vv.z);
            a[6] += blo(vv.w); a[7] += bhi(vv.w);
        }
    }
#pragma unroll
    for (int j = 0; j < 8; j++) {
        a[j] += __shfl_xor(a[j], 8);
        a[j] += __shfl_xor(a[j], 16);
        a[j] += __shfl_xor(a[j], 32);
    }
    if (grp == 0) {
        float invn = 1.0f / fmaxf((float)(r1 - r0), 1.0f);
        uint4 p;
        p.x = (unsigned)f2b(a[0] * invn) | ((unsigned)f2b(a[1] * invn) << 16);
        p.y = (unsigned)f2b(a[2] * invn) | ((unsigned)f2b(a[3] * invn) << 16);
        p.z = (unsigned)f2b(a[4] * invn) | ((unsigned)f2b(a[5] * invn) << 16);
        p.w = (unsigned)f2b(a[6] * invn) | ((unsigned)f2b(a[7] * invn) << 16);
        ((uint4*)aggb)[(size_t)n * 8 + q] = p;
    }
}

// ---------------- MFMA GEMM: out = [agg | self] @ W' + b, per 16-node tile one wave ----------------
template <bool RELU>
__global__ __launch_bounds__(256) void gemm_kernel(const unsigned short* __restrict__ aggb,
                                                   const unsigned short* __restrict__ selfb,
                                                   const unsigned short* __restrict__ pw,
                                                   const float* __restrict__ bias,
                                                   unsigned short* __restrict__ outb) {
    int tile = (blockIdx.x * 256 + threadIdx.x) >> 6;
    if (tile >= N_NODES / 16) return;          // 6250 tiles exactly
    int lane = threadIdx.x & 63;
    int col = lane & 15, quad = lane >> 4;
    int m = tile * 16 + col;
    const uint4* arow = (const uint4*)(aggb + (size_t)m * 64);   // 8 x uint4 per row
    const uint4* srow = (const uint4*)(selfb + (size_t)m * 64);
    // A-frag for k-step s: A[m=lane&15][k = s*32 + quad*8 + j]; k<64 -> agg, k>=64 -> self
    uint4 aa[4];
    aa[0] = arow[quad];
    aa[1] = arow[4 + quad];
    aa[2] = srow[quad];
    aa[3] = srow[4 + quad];
    const uint4* pwv = (const uint4*)pw;
    f32x4 acc[4] = {{0.f,0.f,0.f,0.f},{0.f,0.f,0.f,0.f},{0.f,0.f,0.f,0.f},{0.f,0.f,0.f,0.f}};
    union U { uint4 u; bf16x8 b; };
#pragma unroll
    for (int s = 0; s < 4; s++) {
        U a; a.u = aa[s];
#pragma unroll
        for (int t = 0; t < 4; t++) {
            U bb; bb.u = pwv[(s * 4 + t) * 64 + lane];
            acc[t] = __builtin_amdgcn_mfma_f32_16x16x32_bf16(a.b, bb.b, acc[t], 0, 0, 0);
        }
    }
#pragma unroll
    for (int t = 0; t < 4; t++) {
        float bi = bias[t * 16 + col];
#pragma unroll
        for (int i = 0; i < 4; i++) {
            int node = tile * 16 + quad * 4 + i;   // D: row = quad*4 + reg, col = lane&15
            float v = acc[t][i] + bi;
            if (RELU) v = fmaxf(v, 0.0f);
            outb[(size_t)node * 64 + t * 16 + col] = f2b(v);
        }
    }
}

// ---------------- global add pool over sorted batch (bf16 in) ----------------
__global__ __launch_bounds__(256) void pool_kernel(const unsigned short* __restrict__ hb,
                                                   const int* __restrict__ batch, float* __restrict__ g) {
    int d = threadIdx.x & 63;
    int grp = threadIdx.x >> 6;
    int n0 = blockIdx.x * 256;
    int cur = -1; float acc = 0.f;
    for (int i = grp; i < 256; i += 4) {
        int n = n0 + i;
        if (n >= N_NODES) break;
        int bb = batch[n];
        if (bb != cur) {
            if (cur >= 0) atomicAdd(&g[cur * 64 + d], acc);
            cur = bb; acc = 0.f;
        }
        acc += b2f(hb[(size_t)n * 64 + d]);
    }
    if (cur >= 0) atomicAdd(&g[cur * 64 + d], acc);
}

// ---------------- head: one wave per graph ----------------
__global__ __launch_bounds__(256) void head_kernel(const float* __restrict__ g, const float* __restrict__ Wc1,
                                                   const float* __restrict__ bc1, const float* __restrict__ Wc2,
                                                   const float* __restrict__ bc2, float* __restrict__ out) {
    __shared__ float sg[4][64];
    int tid = threadIdx.x, sub = tid >> 6, lane = tid & 63;
    int gid = blockIdx.x * 4 + sub;
    sg[sub][lane] = g[gid * 64 + lane];
    __syncthreads();
    int j = lane & 31, kh = lane >> 5;
    float a = 0.f;
#pragma unroll
    for (int kk = 0; kk < 32; kk++) {
        int k = kh * 32 + kk;
        a += sg[sub][k] * Wc1[k * 32 + j];
    }
    a += __shfl_xor(a, 32);
    float contrib = (lane < 32) ? fmaxf(a + bc1[j], 0.0f) * Wc2[j] : 0.0f;
    contrib += __shfl_xor(contrib, 16);
    contrib += __shfl_xor(contrib, 8);
    contrib += __shfl_xor(contrib, 4);
    contrib += __shfl_xor(contrib, 2);
    contrib += __shfl_xor(contrib, 1);
    if (lane == 0) out[gid] = contrib + bc2[0];
}

extern "C" void kernel_launch(void* const* d_in, const int* in_sizes, int n_in,
                              void* d_out, int out_size, void* d_ws, size_t ws_size,
                              hipStream_t stream) {
    const float* x   = (const float*)d_in[0];
    const int*   ei  = (const int*)d_in[1];
    const int*   bat = (const int*)d_in[2];
    const float* W1l = (const float*)d_in[3];
    const float* b1  = (const float*)d_in[4];
    const float* W1r = (const float*)d_in[5];
    const float* W2l = (const float*)d_in[6];
    const float* b2  = (const float*)d_in[7];
    const float* W2r = (const float*)d_in[8];
    const float* W3l = (const float*)d_in[9];
    const float* b3  = (const float*)d_in[10];
    const float* W3r = (const float*)d_in[11];
    const float* Wc1 = (const float*)d_in[12];
    const float* bc1 = (const float*)d_in[13];
    const float* Wc2 = (const float*)d_in[14];
    const float* bc2 = (const float*)d_in[15];

    float* ws = (float*)d_ws;
    // ---- workspace layout (float offsets). Each bf16 node buffer = N*64 shorts = 3.2M floats. ----
    int*    rowptr = (int*)(ws);                              // [0, 100352)
    int*    bsum   = (int*)(ws) + 100096;                     // 98 ints inside rowptr pad
    int*    esrc   = (int*)(ws + 100352);                     // [100352, 1300480)
    float*  g      = ws + 1300480;                            // [1300480, 1316864)
    unsigned short* pw2 = (unsigned short*)(ws + 1316864);    // 8192 bf16 = [1316864, 1320960)
    unsigned short* pw3 = (unsigned short*)(ws + 1320960);    // 8192 bf16 = [1320960, 1325056)
    unsigned short* hbA = (unsigned short*)(ws + 1325056);    // [1325056, 4525056)  h1, later h3
    unsigned short* hbB = (unsigned short*)(ws + 4525056);    // [4525056, 7725056)  h2
    unsigned short* agX = (unsigned short*)(ws + 7725056);    // [7725056, 10925056) agg2, later agg3
    int*    ideg   = (int*)hbA;                               // dead before layer1 writes hbA
    int*    cursor = (int*)hbB;                               // dead before gemm2 writes hbB

    hipMemsetAsync(ideg, 0, (size_t)N_NODES * 4, stream);
    hipMemsetAsync(g,    0, (size_t)N_GRAPHS * 64 * 4, stream);

    hist_kernel<<<(N_EDGES + 255) / 256, 256, 0, stream>>>(ei, ideg);
    scan_part<<<NBLK, 256, 0, stream>>>(ideg, bsum);
    scan_block<<<1, 128, 0, stream>>>(bsum);
    scan_final<<<NBLK, 256, 0, stream>>>(ideg, bsum, rowptr, cursor);
    fill_kernel<<<(N_EDGES + 255) / 256, 256, 0, stream>>>(ei, cursor, esrc);
    prepack_kernel<<<64, 256, 0, stream>>>(W2l, W2r, W3l, W3r, pw2, pw3);

    layer1_fused<<<N_NODES / 4, 256, 0, stream>>>(x, rowptr, esrc, W1l, b1, W1r, hbA);

    agg_kernel<<<N_NODES / 4, 256, 0, stream>>>(hbA, rowptr, esrc, agX);
    gemm_kernel<true ><<<(N_NODES / 16 + 3) / 4, 256, 0, stream>>>(agX, hbA, pw2, b2, hbB);

    agg_kernel<<<N_NODES / 4, 256, 0, stream>>>(hbB, rowptr, esrc, agX);
    gemm_kernel<false><<<(N_NODES / 16 + 3) / 4, 256, 0, stream>>>(agX, hbB, pw3, b3, hbA);

    pool_kernel<<<(N_NODES + 255) / 256, 256, 0, stream>>>(hbA, bat, g);
    head_kernel<<<N_GRAPHS / 4, 256, 0, stream>>>(g, Wc1, bc1, Wc2, bc2, (float*)d_out);
}

// Round 9
// 322.127 us; speedup vs baseline: 3.3195x; 1.2751x over previous
//
#include <hip/hip_runtime.h>

#define N_NODES 100000
#define N_EDGES 1200000
#define N_GRAPHS 256
#define NBUCK 392            // buckets of 256 nodes: 392*256 = 100352 >= N
#define EBLK 98              // edge-pass blocks
#define EPB 12245            // ceil(E/98)
#define DCAP 4608            // max edges per bucket handled in LDS (mean 3072, sd 55)

typedef __attribute__((ext_vector_type(8))) short bf16x8;
typedef __attribute__((ext_vector_type(4))) float f32x4;

// ---- bf16 helpers (fp32 <-> bf16 as ushort, RNE) ----
__device__ inline unsigned short f2b(float f) {
    union { float f; unsigned u; } c; c.f = f;
    unsigned u = c.u;
    u += 0x7fff + ((u >> 16) & 1);
    return (unsigned short)(u >> 16);
}
__device__ inline float blo(unsigned u) { union { unsigned i; float f; } c; c.i = u << 16; return c.f; }
__device__ inline float bhi(unsigned u) { union { unsigned i; float f; } c; c.i = u & 0xffff0000u; return c.f; }
__device__ inline float b2f(unsigned short h) { union { unsigned i; float f; } c; c.i = ((unsigned)h) << 16; return c.f; }

// ---------------- bucket phase A: per-(bucket, block) histogram ----------------
__global__ __launch_bounds__(256) void bucketA(const int* __restrict__ ei, int* __restrict__ histm) {
    __shared__ int h[NBUCK];
    int k = blockIdx.x, tid = threadIdx.x;
    for (int t = tid; t < NBUCK; t += 256) h[t] = 0;
    __syncthreads();
    int e0 = k * EPB, e1 = min(e0 + EPB, N_EDGES);
    for (int e = e0 + tid; e < e1; e += 256) {
        int dd = ei[N_EDGES + e];
        atomicAdd(&h[dd >> 8], 1);
    }
    __syncthreads();
    for (int t = tid; t < NBUCK; t += 256) histm[t * EBLK + k] = h[t];
}

// ---------------- phase B: scan histm -> per-(bucket,block) start offsets + bucket starts ----------------
__global__ __launch_bounds__(512) void bucketB(int* __restrict__ histm, int* __restrict__ bstart) {
    __shared__ int sb[512];
    int tid = threadIdx.x;
    int tot = 0;
    if (tid < NBUCK) {
        for (int k = 0; k < EBLK; k++) tot += histm[tid * EBLK + k];
    }
    sb[tid] = tot;
    __syncthreads();
    int acc = tot;
    for (int off = 1; off < 512; off <<= 1) {
        int v = (tid >= off) ? sb[tid - off] : 0;
        __syncthreads();
        sb[tid] = acc = acc + v;
        __syncthreads();
    }
    int excl = acc - tot;          // exclusive prefix for bucket tid
    if (tid < NBUCK) {
        bstart[tid] = excl;
        int run = excl;
        for (int k = 0; k < EBLK; k++) {
            int v = histm[tid * EBLK + k];
            histm[tid * EBLK + k] = run;
            run += v;
        }
    }
    if (tid == 0) bstart[NBUCK] = N_EDGES;
}

// ---------------- phase C: scatter packed (src<<8 | dstlow) into bucket-grouped ebuf ----------------
__global__ __launch_bounds__(256) void bucketC(const int* __restrict__ ei, const int* __restrict__ histm,
                                               int* __restrict__ ebuf) {
    __shared__ int cur[NBUCK];
    int k = blockIdx.x, tid = threadIdx.x;
    for (int t = tid; t < NBUCK; t += 256) cur[t] = histm[t * EBLK + k];
    __syncthreads();
    int e0 = k * EPB, e1 = min(e0 + EPB, N_EDGES);
    for (int e = e0 + tid; e < e1; e += 256) {
        int ss = ei[e];
        int dd = ei[N_EDGES + e];
        int pos = atomicAdd(&cur[dd >> 8], 1);
        ebuf[pos] = (ss << 8) | (dd & 255);
    }
}

// ---------------- phase D: per-bucket counting sort -> rowptr + esrc (coalesced writes) ----------------
__global__ __launch_bounds__(256) void bucketD(const int* __restrict__ ebuf, const int* __restrict__ bstart,
                                               int* __restrict__ rowptr, int* __restrict__ esrc) {
    __shared__ int ecache[DCAP];
    __shared__ int stage[DCAP];
    __shared__ int hist[256], off[256];
    int b = blockIdx.x, tid = threadIdx.x;
    int seg0 = bstart[b], seg1 = bstart[b + 1];
    int cnt = seg1 - seg0;
    hist[tid] = 0;
    int lim = min(cnt, DCAP);
    for (int i = tid; i < lim; i += 256) ecache[i] = ebuf[seg0 + i];
    __syncthreads();
    for (int i = tid; i < cnt; i += 256) {
        int p = (i < DCAP) ? ecache[i] : ebuf[seg0 + i];
        atomicAdd(&hist[p & 255], 1);
    }
    __syncthreads();
    int v = hist[tid];
    off[tid] = v;
    __syncthreads();
    int acc = v;
    for (int o = 1; o < 256; o <<= 1) {
        int t = (tid >= o) ? off[tid - o] : 0;
        __syncthreads();
        off[tid] = acc = acc + t;
        __syncthreads();
    }
    int excl = acc - v;
    rowptr[b * 256 + tid] = seg0 + excl;   // covers rowptr[0..100352); rowptr[N]=E lands correctly
    off[tid] = excl;                       // reuse as local cursor
    __syncthreads();
    if (cnt <= DCAP) {
        for (int i = tid; i < cnt; i += 256) {
            int p = ecache[i];
            int pos = atomicAdd(&off[p & 255], 1);
            stage[pos] = (p >> 8) << 7;    // pre-scaled byte offset (bf16 row = 128 B)
        }
        __syncthreads();
        for (int i = tid; i < cnt; i += 256) esrc[seg0 + i] = stage[i];
    } else {                               // never in practice (cnt > mean+27sd); correctness fallback
        for (int i = tid; i < cnt; i += 256) {
            int p = (i < DCAP) ? ecache[i] : ebuf[seg0 + i];
            int pos = atomicAdd(&off[p & 255], 1);
            esrc[seg0 + pos] = (p >> 8) << 7;
        }
    }
}

// ---------------- prepack W' = [Wl;Wr] (128x64) into MFMA B-fragment order, bf16 ----------------
__global__ __launch_bounds__(256) void prepack_kernel(const float* __restrict__ W2l, const float* __restrict__ W2r,
                                                      const float* __restrict__ W3l, const float* __restrict__ W3r,
                                                      unsigned short* __restrict__ pw2, unsigned short* __restrict__ pw3) {
    int id = blockIdx.x * 256 + threadIdx.x;   // 16384 total
    int layer = id >> 13;
    int r = id & 8191;
    int j = r & 7, lane = (r >> 3) & 63, t = (r >> 9) & 3, s = (r >> 11) & 3;
    int k = s * 32 + (lane >> 4) * 8 + j;
    int n = t * 16 + (lane & 15);
    const float* Wl = layer ? W3l : W2l;
    const float* Wr = layer ? W3r : W2r;
    float v = (k < 64) ? Wl[k * 64 + n] : Wr[(k - 64) * 64 + n];
    unsigned short* dst = layer ? pw3 : pw2;
    dst[r] = f2b(v);
}

// ---------------- layer 1: fp32 x gather (32 edges/instr) -> bf16 out ----------------
__global__ __launch_bounds__(256) void layer1_fused(const float* __restrict__ x, const int* __restrict__ rowptr,
                                                    const int* __restrict__ esrc,
                                                    const float* __restrict__ Wl, const float* __restrict__ b,
                                                    const float* __restrict__ Wr, unsigned short* __restrict__ ob) {
    __shared__ float sa[4][8], sx[4][8];
    int tid = threadIdx.x;
    int sub = tid >> 6, lane = tid & 63;
    int j = lane >> 1, half = lane & 1;        // 32 edges x 2 float4-halves
    int n = blockIdx.x * 4 + sub;
    int r0 = __builtin_amdgcn_readfirstlane(rowptr[n]);
    int r1 = __builtin_amdgcn_readfirstlane(rowptr[n + 1]);
    const float4* x4 = (const float4*)x;
    float ax = 0.f, ay = 0.f, az = 0.f, aw = 0.f;
    for (int e = r0; e < r1; e += 32) {
        int idx = e + j;
        if (idx < r1) {
            int off = esrc[idx];               // src*128; x row = 32 B -> x4 index = off>>6
            float4 v = x4[(off >> 6) + half];
            ax += v.x; ay += v.y; az += v.z; aw += v.w;
        }
    }
#pragma unroll
    for (int m = 2; m <= 32; m <<= 1) {
        ax += __shfl_xor(ax, m); ay += __shfl_xor(ay, m);
        az += __shfl_xor(az, m); aw += __shfl_xor(aw, m);
    }
    float invn = 1.0f / fmaxf((float)(r1 - r0), 1.0f);
    if (lane < 2) {
        float4 xs = x4[(size_t)n * 2 + lane];
        float4 av; av.x = ax * invn; av.y = ay * invn; av.z = az * invn; av.w = aw * invn;
        ((float4*)sa[sub])[lane] = av;
        ((float4*)sx[sub])[lane] = xs;
    }
    __syncthreads();
    float al = 0.f, ar = 0.f;
#pragma unroll
    for (int kk = 0; kk < 8; kk++) {
        al += sa[sub][kk] * Wl[kk * 64 + lane];
        ar += sx[sub][kk] * Wr[kk * 64 + lane];
    }
    ob[(size_t)n * 64 + lane] = f2b(fmaxf(al + b[lane] + ar, 0.0f));
}

// ---------------- gather-mean only: bf16 rows, 8 edges/instr, 24 in flight, no LDS ----------------
__global__ __launch_bounds__(256) void agg_kernel(const unsigned short* __restrict__ hb,
                                                  const int* __restrict__ rowptr,
                                                  const int* __restrict__ esrc,
                                                  unsigned short* __restrict__ aggb) {
    int tid = threadIdx.x;
    int sub = tid >> 6, lane = tid & 63;
    int grp = lane >> 3, q = lane & 7;         // 8 edge-groups x 8 uint4-lanes (16 B each)
    int n = blockIdx.x * 4 + sub;
    int r0 = __builtin_amdgcn_readfirstlane(rowptr[n]);
    int r1 = __builtin_amdgcn_readfirstlane(rowptr[n + 1]);
    const uint4* h16 = (const uint4*)hb;
    uint4 v[3];
#pragma unroll
    for (int c = 0; c < 3; c++) {
        uint4 vv; vv.x = 0u; vv.y = 0u; vv.z = 0u; vv.w = 0u;
        int idx = r0 + 8 * c + grp;
        if (idx < r1) {
            int off = esrc[idx];
            vv = h16[(off >> 4) + q];
        }
        v[c] = vv;
    }
    float a[8];
#pragma unroll
    for (int j = 0; j < 8; j++) a[j] = 0.f;
#pragma unroll
    for (int c = 0; c < 3; c++) {
        a[0] += blo(v[c].x); a[1] += bhi(v[c].x);
        a[2] += blo(v[c].y); a[3] += bhi(v[c].y);
        a[4] += blo(v[c].z); a[5] += bhi(v[c].z);
        a[6] += blo(v[c].w); a[7] += bhi(v[c].w);
    }
    for (int e = r0 + 24; e < r1; e += 8) {    // rare tail (deg > 24)
        int idx = e + grp;
        if (idx < r1) {
            int off = esrc[idx];
            uint4 vv = h16[(off >> 4) + q];
            a[0] += blo(vv.x); a[1] += bhi(vv.x);
            a[2] += blo(vv.y); a[3] += bhi(vv.y);
            a[4] += blo(vv.z); a[5] += bhi(vv.z);
            a[6] += blo(vv.w); a[7] += bhi(vv.w);
        }
    }
#pragma unroll
    for (int j = 0; j < 8; j++) {
        a[j] += __shfl_xor(a[j], 8);
        a[j] += __shfl_xor(a[j], 16);
        a[j] += __shfl_xor(a[j], 32);
    }
    if (grp == 0) {
        float invn = 1.0f / fmaxf((float)(r1 - r0), 1.0f);
        uint4 p;
        p.x = (unsigned)f2b(a[0] * invn) | ((unsigned)f2b(a[1] * invn) << 16);
        p.y = (unsigned)f2b(a[2] * invn) | ((unsigned)f2b(a[3] * invn) << 16);
        p.z = (unsigned)f2b(a[4] * invn) | ((unsigned)f2b(a[5] * invn) << 16);
        p.w = (unsigned)f2b(a[6] * invn) | ((unsigned)f2b(a[7] * invn) << 16);
        ((uint4*)aggb)[(size_t)n * 8 + q] = p;
    }
}

// ---------------- MFMA GEMM: out = [agg | self] @ W' + b, per 16-node tile one wave ----------------
template <bool RELU>
__global__ __launch_bounds__(256) void gemm_kernel(const unsigned short* __restrict__ aggb,
                                                   const unsigned short* __restrict__ selfb,
                                                   const unsigned short* __restrict__ pw,
                                                   const float* __restrict__ bias,
                                                   unsigned short* __restrict__ outb) {
    int tile = (blockIdx.x * 256 + threadIdx.x) >> 6;
    if (tile >= N_NODES / 16) return;          // 6250 tiles exactly
    int lane = threadIdx.x & 63;
    int col = lane & 15, quad = lane >> 4;
    int m = tile * 16 + col;
    const uint4* arow = (const uint4*)(aggb + (size_t)m * 64);
    const uint4* srow = (const uint4*)(selfb + (size_t)m * 64);
    uint4 aa[4];
    aa[0] = arow[quad];
    aa[1] = arow[4 + quad];
    aa[2] = srow[quad];
    aa[3] = srow[4 + quad];
    const uint4* pwv = (const uint4*)pw;
    f32x4 acc[4] = {{0.f,0.f,0.f,0.f},{0.f,0.f,0.f,0.f},{0.f,0.f,0.f,0.f},{0.f,0.f,0.f,0.f}};
    union U { uint4 u; bf16x8 b; };
#pragma unroll
    for (int s = 0; s < 4; s++) {
        U a; a.u = aa[s];
#pragma unroll
        for (int t = 0; t < 4; t++) {
            U bb; bb.u = pwv[(s * 4 + t) * 64 + lane];
            acc[t] = __builtin_amdgcn_mfma_f32_16x16x32_bf16(a.b, bb.b, acc[t], 0, 0, 0);
        }
    }
#pragma unroll
    for (int t = 0; t < 4; t++) {
        float bi = bias[t * 16 + col];
#pragma unroll
        for (int i = 0; i < 4; i++) {
            int node = tile * 16 + quad * 4 + i;   // D: row = quad*4 + reg, col = lane&15
            float v = acc[t][i] + bi;
            if (RELU) v = fmaxf(v, 0.0f);
            outb[(size_t)node * 64 + t * 16 + col] = f2b(v);
        }
    }
}

// ---------------- global add pool over sorted batch (bf16 in) ----------------
__global__ __launch_bounds__(256) void pool_kernel(const unsigned short* __restrict__ hb,
                                                   const int* __restrict__ batch, float* __restrict__ g) {
    int d = threadIdx.x & 63;
    int grp = threadIdx.x >> 6;
    int n0 = blockIdx.x * 256;
    int cur = -1; float acc = 0.f;
    for (int i = grp; i < 256; i += 4) {
        int n = n0 + i;
        if (n >= N_NODES) break;
        int bb = batch[n];
        if (bb != cur) {
            if (cur >= 0) atomicAdd(&g[cur * 64 + d], acc);
            cur = bb; acc = 0.f;
        }
        acc += b2f(hb[(size_t)n * 64 + d]);
    }
    if (cur >= 0) atomicAdd(&g[cur * 64 + d], acc);
}

// ---------------- head: one wave per graph ----------------
__global__ __launch_bounds__(256) void head_kernel(const float* __restrict__ g, const float* __restrict__ Wc1,
                                                   const float* __restrict__ bc1, const float* __restrict__ Wc2,
                                                   const float* __restrict__ bc2, float* __restrict__ out) {
    __shared__ float sg[4][64];
    int tid = threadIdx.x, sub = tid >> 6, lane = tid & 63;
    int gid = blockIdx.x * 4 + sub;
    sg[sub][lane] = g[gid * 64 + lane];
    __syncthreads();
    int j = lane & 31, kh = lane >> 5;
    float a = 0.f;
#pragma unroll
    for (int kk = 0; kk < 32; kk++) {
        int k = kh * 32 + kk;
        a += sg[sub][k] * Wc1[k * 32 + j];
    }
    a += __shfl_xor(a, 32);
    float contrib = (lane < 32) ? fmaxf(a + bc1[j], 0.0f) * Wc2[j] : 0.0f;
    contrib += __shfl_xor(contrib, 16);
    contrib += __shfl_xor(contrib, 8);
    contrib += __shfl_xor(contrib, 4);
    contrib += __shfl_xor(contrib, 2);
    contrib += __shfl_xor(contrib, 1);
    if (lane == 0) out[gid] = contrib + bc2[0];
}

extern "C" void kernel_launch(void* const* d_in, const int* in_sizes, int n_in,
                              void* d_out, int out_size, void* d_ws, size_t ws_size,
                              hipStream_t stream) {
    const float* x   = (const float*)d_in[0];
    const int*   ei  = (const int*)d_in[1];
    const int*   bat = (const int*)d_in[2];
    const float* W1l = (const float*)d_in[3];
    const float* b1  = (const float*)d_in[4];
    const float* W1r = (const float*)d_in[5];
    const float* W2l = (const float*)d_in[6];
    const float* b2  = (const float*)d_in[7];
    const float* W2r = (const float*)d_in[8];
    const float* W3l = (const float*)d_in[9];
    const float* b3  = (const float*)d_in[10];
    const float* W3r = (const float*)d_in[11];
    const float* Wc1 = (const float*)d_in[12];
    const float* bc1 = (const float*)d_in[13];
    const float* Wc2 = (const float*)d_in[14];
    const float* bc2 = (const float*)d_in[15];

    float* ws = (float*)d_ws;
    // ---- workspace layout (float offsets). bf16 node buffer = N*64 shorts = 3.2M floats. ----
    int*    rowptr = (int*)(ws);                              // [0, 100352)
    int*    esrc   = (int*)(ws + 100352);                     // [100352, 1300480)
    float*  g      = ws + 1300480;                            // [1300480, 1316864)
    unsigned short* pw2 = (unsigned short*)(ws + 1316864);    // 8192 bf16
    unsigned short* pw3 = (unsigned short*)(ws + 1320960);    // 8192 bf16
    unsigned short* hbA = (unsigned short*)(ws + 1325056);    // h1, later h3
    unsigned short* hbB = (unsigned short*)(ws + 4525056);    // h2
    unsigned short* agX = (unsigned short*)(ws + 7725056);    // agg2, later agg3
    int*    ebuf   = (int*)(ws + 10925056);                   // 1200000 packed edges
    int*    histm  = (int*)(ws + 12125184);                   // 392*98 = 38416
    int*    bstart = (int*)(ws + 12163600);                   // 393

    hipMemsetAsync(g, 0, (size_t)N_GRAPHS * 64 * 4, stream);

    bucketA<<<EBLK, 256, 0, stream>>>(ei, histm);
    bucketB<<<1, 512, 0, stream>>>(histm, bstart);
    bucketC<<<EBLK, 256, 0, stream>>>(ei, histm, ebuf);
    bucketD<<<NBUCK, 256, 0, stream>>>(ebuf, bstart, rowptr, esrc);
    prepack_kernel<<<64, 256, 0, stream>>>(W2l, W2r, W3l, W3r, pw2, pw3);

    layer1_fused<<<N_NODES / 4, 256, 0, stream>>>(x, rowptr, esrc, W1l, b1, W1r, hbA);

    agg_kernel<<<N_NODES / 4, 256, 0, stream>>>(hbA, rowptr, esrc, agX);
    gemm_kernel<true ><<<(N_NODES / 16 + 3) / 4, 256, 0, stream>>>(agX, hbA, pw2, b2, hbB);

    agg_kernel<<<N_NODES / 4, 256, 0, stream>>>(hbB, rowptr, esrc, agX);
    gemm_kernel<false><<<(N_NODES / 16 + 3) / 4, 256, 0, stream>>>(agX, hbB, pw3, b3, hbA);

    pool_kernel<<<(N_NODES + 255) / 256, 256, 0, stream>>>(hbA, bat, g);
    head_kernel<<<N_GRAPHS / 4, 256, 0, stream>>>(g, Wc1, bc1, Wc2, bc2, (float*)d_out);
}